// Round 2
// baseline (5363.557 us; speedup 1.0000x reference)
//
#include <hip/hip_runtime.h>

#define NN 16777216   // 4*256*64*256
#define CC 256
#define FF 64
#define TT 256
#define CH_ROWS 8192
#define NCH 8

// ---------------- helpers ----------------
__device__ __forceinline__ void blockReduce2(float& a, float& b, float* sbuf) {
  #pragma unroll
  for (int off = 32; off > 0; off >>= 1) {
    a += __shfl_down(a, off, 64);
    b += __shfl_down(b, off, 64);
  }
  int w = threadIdx.x >> 6;
  if ((threadIdx.x & 63) == 0) { sbuf[w] = a; sbuf[4 + w] = b; }
  __syncthreads();
  if (threadIdx.x == 0) {
    a = sbuf[0] + sbuf[1] + sbuf[2] + sbuf[3];
    b = sbuf[4] + sbuf[5] + sbuf[6] + sbuf[7];
  }
}

__global__ void zero_stats_k(float* p) { p[threadIdx.x] = 0.f; }

// ---------------- GroupNorm (NCHW contiguous groups: 131072 elems/group) ----------------
__global__ __launch_bounds__(256) void gn_stats_contig(const float* __restrict__ src, float* __restrict__ stats) {
  __shared__ float sbuf[8];
  int grp = blockIdx.x >> 3, chunk = blockIdx.x & 7;
  const float4* p = (const float4*)src + grp * 32768 + chunk * 4096;
  float s = 0.f, ss = 0.f;
  for (int i = threadIdx.x; i < 4096; i += 256) {
    float4 v = p[i];
    s += v.x + v.y + v.z + v.w;
    ss += v.x * v.x + v.y * v.y + v.z * v.z + v.w * v.w;
  }
  blockReduce2(s, ss, sbuf);
  if (threadIdx.x == 0) { atomicAdd(&stats[grp], s); atomicAdd(&stats[128 + grp], ss); }
}

__global__ __launch_bounds__(256) void gn_apply_contig(const float* __restrict__ src, const float* __restrict__ stats,
    float* __restrict__ dst, float eps, const float* __restrict__ resid, const float* __restrict__ gate) {
  int i4 = blockIdx.x * 256 + threadIdx.x;   // 4194304 float4
  int gi = i4 >> 15;
  float mean = stats[gi] * (1.f / 131072.f);
  float var = stats[128 + gi] * (1.f / 131072.f) - mean * mean;
  float r = rsqrtf(var + eps);
  float4 v = ((const float4*)src)[i4];
  float4 o;
  o.x = (v.x - mean) * r; o.y = (v.y - mean) * r; o.z = (v.z - mean) * r; o.w = (v.w - mean) * r;
  if (resid) {
    float g = gate[0];
    float4 x = ((const float4*)resid)[i4];
    o.x = x.x + g * o.x; o.y = x.y + g * o.y; o.z = x.z + g * o.z; o.w = x.w + g * o.w;
  }
  ((float4*)dst)[i4] = o;
}

// ---------------- conv 3x3 ----------------
__global__ void transpose_w_k(const float* __restrict__ w, float* __restrict__ wT) {
  int s = blockIdx.x * 256 + threadIdx.x;
  if (s < 589824) {
    int co = s / 2304, r = s % 2304;       // r = ci*9 + tap
    wT[r * 256 + co] = w[s];
  }
}

// wT layout [ci][tap][co]; grid (T/64, F, B*4); mode=1: +bias +g_diff*temb, silu
__global__ __launch_bounds__(256) void conv3x3_k(const float* __restrict__ in, const float* __restrict__ wT,
    const float* __restrict__ bias, const float* __restrict__ temb, const float* __restrict__ gd,
    float* __restrict__ out, int mode) {
  __shared__ __align__(16) float sW[4][9][64];
  __shared__ __align__(16) float sI[4][3][72];
  int t0 = blockIdx.x * 64;
  int f = blockIdx.y;
  int b = blockIdx.z >> 2;
  int co0 = (blockIdx.z & 3) * 64;
  int tid = threadIdx.x;
  int tx = tid & 15, ty = tid >> 4;
  float acc[4][4] = {};
  for (int ci0 = 0; ci0 < 256; ci0 += 4) {
    __syncthreads();
    for (int s = tid; s < 2304; s += 256) {
      int co = s & 63, tap = (s >> 6) % 9, c = s / 576;
      sW[c][tap][co] = wT[(ci0 + c) * 2304 + tap * 256 + co0 + co];
    }
    for (int s = tid; s < 792; s += 256) {
      int c = s / 198, rem = s - c * 198;
      int r = rem / 66, k = rem - r * 66;
      int fi = f - 1 + r, tg = t0 - 1 + k;
      float v = 0.f;
      if (fi >= 0 && fi < FF && tg >= 0 && tg < TT)
        v = in[((b * CC + ci0 + c) * FF + fi) * TT + tg];
      sI[c][r][k] = v;
    }
    __syncthreads();
    #pragma unroll
    for (int c = 0; c < 4; ++c) {
      #pragma unroll
      for (int df = 0; df < 3; ++df) {
        const float* ir = &sI[c][df][tx * 4];
        float iv[6];
        #pragma unroll
        for (int j = 0; j < 6; ++j) iv[j] = ir[j];
        #pragma unroll
        for (int dt = 0; dt < 3; ++dt) {
          const float* wr = &sW[c][df * 3 + dt][ty * 4];
          float w0 = wr[0], w1 = wr[1], w2 = wr[2], w3 = wr[3];
          #pragma unroll
          for (int j = 0; j < 4; ++j) {
            float x = iv[dt + j];
            acc[0][j] += w0 * x;
            acc[1][j] += w1 * x;
            acc[2][j] += w2 * x;
            acc[3][j] += w3 * x;
          }
        }
      }
    }
  }
  float gdv = mode ? gd[0] : 0.f;
  #pragma unroll
  for (int i = 0; i < 4; ++i) {
    int co = co0 + ty * 4 + i;
    float bb = 0.f;
    if (mode) bb = bias[co] + gdv * temb[b * CC + co];
    #pragma unroll
    for (int j = 0; j < 4; ++j) {
      float v = acc[i][j] + bb;
      if (mode) v = v / (1.f + expf(-v));   // silu
      out[((b * CC + co) * FF + f) * TT + t0 + tx * 4 + j] = v;
    }
  }
}

// ---------------- GEMM: C[M,N] = gn?(A[M,256]) @ B[256,N] (+bias), strided ----------------
__global__ __launch_bounds__(256) void gemm_k(const float* __restrict__ A, int lda,
    const float* __restrict__ Bm, int N, const float* __restrict__ bias,
    float* __restrict__ Cm, int ldc,
    const float* __restrict__ gstats, int growbase, float eps) {
  __shared__ __align__(16) float sA[16][64];
  __shared__ __align__(16) float sB[16][64];
  int n0 = blockIdx.x * 64, m0 = blockIdx.y * 64;
  int tid = threadIdx.x;
  int tx = tid & 15, ty = tid >> 4;
  int arow = m0 + (tid >> 2), acol = (tid & 3) * 4;
  int brow = tid >> 4, bcol = (tid & 15) * 4;
  float acc[4][4] = {};
  for (int k0 = 0; k0 < 256; k0 += 16) {
    __syncthreads();
    float4 av = *(const float4*)&A[(size_t)arow * lda + k0 + acol];
    if (gstats) {
      int gr = growbase + arow;
      int grp = (gr >> 14) * 32 + ((k0 + acol) >> 3);
      float mean = gstats[grp] * (1.f / 131072.f);
      float var = gstats[128 + grp] * (1.f / 131072.f) - mean * mean;
      float rr = rsqrtf(var + eps);
      av.x = (av.x - mean) * rr; av.y = (av.y - mean) * rr;
      av.z = (av.z - mean) * rr; av.w = (av.w - mean) * rr;
    }
    sA[acol + 0][tid >> 2] = av.x;
    sA[acol + 1][tid >> 2] = av.y;
    sA[acol + 2][tid >> 2] = av.z;
    sA[acol + 3][tid >> 2] = av.w;
    *(float4*)&sB[brow][bcol] = *(const float4*)&Bm[(k0 + brow) * N + n0 + bcol];
    __syncthreads();
    #pragma unroll
    for (int kk = 0; kk < 16; ++kk) {
      float4 a = *(const float4*)&sA[kk][ty * 4];
      float4 b = *(const float4*)&sB[kk][tx * 4];
      float aa[4] = {a.x, a.y, a.z, a.w};
      float bb[4] = {b.x, b.y, b.z, b.w};
      #pragma unroll
      for (int i = 0; i < 4; ++i)
        #pragma unroll
        for (int j = 0; j < 4; ++j)
          acc[i][j] += aa[i] * bb[j];
    }
  }
  #pragma unroll
  for (int i = 0; i < 4; ++i)
    #pragma unroll
    for (int j = 0; j < 4; ++j) {
      int n = n0 + tx * 4 + j;
      float v = acc[i][j];
      if (bias) v += bias[n];
      Cm[(size_t)(m0 + ty * 4 + i) * ldc + n] = v;
    }
}

// ---------------- transposes ----------------
// XF[(b*T+t)][f][c] = X1[b][c][f][t]
__global__ __launch_bounds__(256) void x1_to_xf_k(const float* __restrict__ X1, float* __restrict__ XF) {
  __shared__ float sT[32][33];
  int bx = blockIdx.x;
  int r = bx >> 6;               // b*64+f
  int c0 = ((bx >> 3) & 7) * 32;
  int t0 = (bx & 7) * 32;
  int b = r >> 6, f = r & 63;
  int tl = threadIdx.x & 31, tr = threadIdx.x >> 5;
  #pragma unroll
  for (int i = 0; i < 4; ++i) {
    int c = c0 + tr + i * 8;
    sT[tr + i * 8][tl] = X1[((b * CC + c) * FF + f) * TT + t0 + tl];   // [c_local][t_local]
  }
  __syncthreads();
  #pragma unroll
  for (int i = 0; i < 4; ++i) {
    int t = t0 + tr + i * 8;
    XF[((b * TT + t) * FF + f) * CC + c0 + tl] = sT[tl][tr + i * 8];
  }
}

// XT[(b*64+f)][t][c] = XF[(b*256+t)][f][c]
__global__ __launch_bounds__(256) void xf_to_xt_k(const float* __restrict__ XF, float* __restrict__ XT) {
  int rowid = blockIdx.x * 4 + (threadIdx.x >> 6);   // b*16384 + f*256 + t
  int lane = threadIdx.x & 63;
  int b = rowid >> 14, f = (rowid >> 8) & 63, t = rowid & 255;
  int src = ((b * TT + t) * FF + f) * CC + lane * 4;
  int dst = rowid * CC + lane * 4;
  *(float4*)&XT[dst] = *(const float4*)&XF[src];
}

// out[b][c][f][t] = XT[rg][t][c] + O2local[rl][t][c]   (per-chunk, rl in [0,32))
__global__ __launch_bounds__(256) void final_out_k(const float* __restrict__ XT, const float* __restrict__ O2,
                                                   float* __restrict__ out, int rbase) {
  __shared__ float sT[32][33];
  int bx = blockIdx.x;           // 2048: rl(5b) t0(3b) c0(3b)
  int rl = bx >> 6;
  int t0 = ((bx >> 3) & 7) * 32;
  int c0 = (bx & 7) * 32;
  int rg = rbase + rl;
  int b = rg >> 6, f = rg & 63;
  int tc = threadIdx.x & 31, tr = threadIdx.x >> 5;
  #pragma unroll
  for (int i = 0; i < 4; ++i) {
    int t = t0 + tr + i * 8;
    sT[tr + i * 8][tc] = XT[rg * 65536 + t * 256 + c0 + tc] + O2[rl * 65536 + t * 256 + c0 + tc];
  }
  __syncthreads();
  #pragma unroll
  for (int i = 0; i < 4; ++i) {
    int c = c0 + tr + i * 8;
    out[((b * CC + c) * FF + f) * TT + t0 + tc] = sT[tc][tr + i * 8];
  }
}

// ---------------- attention: frequency axis (seq 64), in-place y -> q columns ----------------
__global__ __launch_bounds__(256) void attn2_k(float* __restrict__ Q) {
  __shared__ float sq[64][33], sk[64][33], sv[64][33];
  __shared__ float sS[64][65];
  __shared__ float sInv[64];
  int bt = blockIdx.x >> 3, h = blockIdx.x & 7;    // bt local in [0,128)
  int tid = threadIdx.x;
  const float scale = 0.17677669529663687f;
  for (int s = tid; s < 2048; s += 256) {
    int fq = s >> 5, d = s & 31;
    int base = (bt * 64 + fq) * 768 + h * 32 + d;
    sq[fq][d] = Q[base];
    sk[fq][d] = Q[base + 256];
    sv[fq][d] = Q[base + 512];
  }
  __syncthreads();
  {
    int L = tid >> 2, lg = tid & 3;
    float a[16] = {};
    for (int d = 0; d < 32; ++d) {
      float qv = sq[L][d];
      #pragma unroll
      for (int j = 0; j < 16; ++j) a[j] += qv * sk[lg * 16 + j][d];
    }
    #pragma unroll
    for (int j = 0; j < 16; ++j) sS[L][lg * 16 + j] = a[j] * scale;
  }
  __syncthreads();
  if (tid < 64) {
    float mx = -1e30f;
    for (int l = 0; l < 64; ++l) mx = fmaxf(mx, sS[tid][l]);
    float sum = 0.f;
    for (int l = 0; l < 64; ++l) { float e = expf(sS[tid][l] - mx); sS[tid][l] = e; sum += e; }
    sInv[tid] = 1.f / sum;
  }
  __syncthreads();
  {
    int L = tid >> 2, dg = tid & 3;
    float a[8] = {};
    for (int l = 0; l < 64; ++l) {
      float p = sS[L][l];
      #pragma unroll
      for (int j = 0; j < 8; ++j) a[j] += p * sv[l][dg * 8 + j];
    }
    float r = sInv[L];
    #pragma unroll
    for (int j = 0; j < 8; ++j)
      Q[(bt * 64 + L) * 768 + h * 32 + dg * 8 + j] = a[j] * r;   // overwrite own q columns
  }
}

// ---------------- attention: global time (pooled q, seq 256) ----------------
__global__ __launch_bounds__(256) void attn3_k(const float* __restrict__ Q3, float* __restrict__ y3, int bf_base) {
  __shared__ float part[8][32];
  __shared__ float sqm[32];
  __shared__ float sp[256];
  __shared__ float sred[256];
  int bfl = blockIdx.x >> 3, h = blockIdx.x & 7;   // bfl in [0,32)
  int tid = threadIdx.x;
  int tg = tid >> 5, d = tid & 31;
  const float scale = 0.17677669529663687f;
  int rowbase = bfl * 256;
  float s = 0.f;
  for (int t = tg * 32; t < tg * 32 + 32; ++t) s += Q3[(rowbase + t) * 768 + h * 32 + d];
  part[tg][d] = s;
  __syncthreads();
  if (tid < 32) {
    float m = 0.f;
    for (int g = 0; g < 8; ++g) m += part[g][tid];
    sqm[tid] = m * (1.f / 256.f);
  }
  __syncthreads();
  {
    float dot = 0.f;
    const float* kp = &Q3[(rowbase + tid) * 768 + 256 + h * 32];
    for (int dd = 0; dd < 32; ++dd) dot += sqm[dd] * kp[dd];
    sp[tid] = dot * scale;
    sred[tid] = sp[tid];
  }
  __syncthreads();
  for (int st = 128; st > 0; st >>= 1) { if (tid < st) sred[tid] = fmaxf(sred[tid], sred[tid + st]); __syncthreads(); }
  float mx = sred[0];
  __syncthreads();
  float e = expf(sp[tid] - mx);
  sred[tid] = e;
  __syncthreads();
  for (int st = 128; st > 0; st >>= 1) { if (tid < st) sred[tid] += sred[tid + st]; __syncthreads(); }
  float rinv = 1.f / sred[0];
  sp[tid] = e * rinv;
  __syncthreads();
  float acc = 0.f;
  for (int t = tg * 32; t < tg * 32 + 32; ++t) acc += sp[t] * Q3[(rowbase + t) * 768 + 512 + h * 32 + d];
  part[tg][d] = acc;
  __syncthreads();
  if (tid < 32) {
    float o = 0.f;
    for (int g = 0; g < 8; ++g) o += part[g][tid];
    y3[(bf_base + bfl) * 256 + h * 32 + tid] = o;
  }
}

// ---------------- LSA: local window 16 along T, in-place o -> q columns ----------------
__global__ __launch_bounds__(256) void lsa_attn_k(float* __restrict__ Q4) {
  __shared__ __align__(16) float sX[16][772];
  __shared__ float sS[8][16][17];
  __shared__ float sInv[8][16];
  int bfl = blockIdx.x >> 4, w = blockIdx.x & 15;   // bfl in [0,32)
  int tid = threadIdx.x;
  int rb = (bfl * 256 + w * 16) * 768;
  for (int s = tid; s < 3072; s += 256) {
    int t = s / 192, c4 = s % 192;
    *(float4*)&sX[t][c4 * 4] = *(const float4*)&Q4[rb + t * 768 + c4 * 4];
  }
  __syncthreads();
  const float scale = 0.17677669529663687f;
  #pragma unroll
  for (int rep = 0; rep < 8; ++rep) {
    int idx = tid + rep * 256;
    int h = idx >> 8, q = (idx >> 4) & 15, k = idx & 15;
    float dot = 0.f;
    const float* qp = &sX[q][h * 32];
    const float* kp = &sX[k][256 + h * 32];
    for (int d = 0; d < 32; ++d) dot += qp[d] * kp[d];
    sS[h][q][k] = dot * scale;
  }
  __syncthreads();
  if (tid < 128) {
    int h = tid >> 4, q = tid & 15;
    float mx = -1e30f;
    for (int k = 0; k < 16; ++k) mx = fmaxf(mx, sS[h][q][k]);
    float sum = 0.f;
    for (int k = 0; k < 16; ++k) { float e = expf(sS[h][q][k] - mx); sS[h][q][k] = e; sum += e; }
    sInv[h][q] = 1.f / sum;
  }
  __syncthreads();
  #pragma unroll
  for (int rep = 0; rep < 16; ++rep) {
    int idx = tid + rep * 256;
    int t = idx >> 8, c = idx & 255;
    int h = c >> 5;
    float acc = 0.f;
    for (int k = 0; k < 16; ++k) acc += sS[h][t][k] * sX[k][512 + c];
    Q4[rb + t * 768 + c] = acc * sInv[h][t];   // overwrite own q columns
  }
}

// ---------------- per-row GroupNorm (8-ch groups), fused residual add ----------------
// xf[row][c] += gate * gn(y2[row][c]); 8192 rows x 32 groups per chunk
__global__ __launch_bounds__(256) void gn_rows_add_k(const float* __restrict__ y2, float* __restrict__ xf,
                                                     const float* __restrict__ gate) {
  int s = blockIdx.x * 256 + threadIdx.x;   // 262144
  int base = s * 8;
  float4 a = *(const float4*)&y2[base];
  float4 b = *(const float4*)&y2[base + 4];
  float m = (a.x + a.y + a.z + a.w + b.x + b.y + b.z + b.w) * 0.125f;
  float q = (a.x * a.x + a.y * a.y + a.z * a.z + a.w * a.w +
             b.x * b.x + b.y * b.y + b.z * b.z + b.w * b.w) * 0.125f - m * m;
  float r = rsqrtf(q + 1e-5f);
  float g = gate[0];
  float4 xa = *(const float4*)&xf[base];
  float4 xb = *(const float4*)&xf[base + 4];
  xa.x += g * (a.x - m) * r; xa.y += g * (a.y - m) * r; xa.z += g * (a.z - m) * r; xa.w += g * (a.w - m) * r;
  xb.x += g * (b.x - m) * r; xb.y += g * (b.y - m) * r; xb.z += g * (b.z - m) * r; xb.w += g * (b.w - m) * r;
  *(float4*)&xf[base] = xa;
  *(float4*)&xf[base + 4] = xb;
}

__global__ void gn_rows_k(const float* __restrict__ src, float* __restrict__ dst, int total) {
  int s = blockIdx.x * 256 + threadIdx.x;
  if (s >= total) return;
  int base = s * 8;
  float4 a = *(const float4*)&src[base];
  float4 b = *(const float4*)&src[base + 4];
  float m = (a.x + a.y + a.z + a.w + b.x + b.y + b.z + b.w) * 0.125f;
  float q = (a.x * a.x + a.y * a.y + a.z * a.z + a.w * a.w +
             b.x * b.x + b.y * b.y + b.z * b.z + b.w * b.w) * 0.125f - m * m;
  float r = rsqrtf(q + 1e-5f);
  a.x = (a.x - m) * r; a.y = (a.y - m) * r; a.z = (a.z - m) * r; a.w = (a.w - m) * r;
  b.x = (b.x - m) * r; b.y = (b.y - m) * r; b.z = (b.z - m) * r; b.w = (b.w - m) * r;
  *(float4*)&dst[base] = a;
  *(float4*)&dst[base + 4] = b;
}

// XT[r][t][c] += gate * y3n[r][c]
__global__ __launch_bounds__(256) void bcast_add_k(float* __restrict__ XT, const float* __restrict__ y3n,
                                                   const float* __restrict__ gate) {
  int i4 = blockIdx.x * 256 + threadIdx.x;
  int flat = i4 * 4;
  int r = flat >> 16, c = flat & 255;
  float g = gate[0];
  float4 v = ((float4*)XT)[i4];
  float4 a = *(const float4*)&y3n[r * 256 + c];
  v.x += g * a.x; v.y += g * a.y; v.z += g * a.z; v.w += g * a.w;
  ((float4*)XT)[i4] = v;
}

// ---------------- GroupNorm stats over XT layout [bf][t][c] per (b, g) ----------------
__global__ __launch_bounds__(256) void gn_stats_xt_k(const float* __restrict__ X, float* __restrict__ stats) {
  __shared__ float sbuf[8];
  int bx = blockIdx.x;                 // b(2b) g(5b) f(6b) = 8192
  int b = bx >> 11, g = (bx >> 6) & 31, f = bx & 63;
  int base = (b * 64 + f) * 65536 + g * 8;
  float s = 0.f, ss = 0.f;
  for (int i = threadIdx.x; i < 2048; i += 256) {
    int t = i >> 3, c = i & 7;
    float v = X[base + t * 256 + c];
    s += v; ss += v * v;
  }
  blockReduce2(s, ss, sbuf);
  if (threadIdx.x == 0) { atomicAdd(&stats[b * 32 + g], s); atomicAdd(&stats[128 + b * 32 + g], ss); }
}

// ---------------- launch ----------------
extern "C" void kernel_launch(void* const* d_in, const int* in_sizes, int n_in,
                              void* d_out, int out_size, void* d_ws, size_t ws_size,
                              hipStream_t stream) {
  (void)in_sizes; (void)n_in; (void)out_size; (void)ws_size;
  const float* x        = (const float*)d_in[0];
  const float* temb     = (const float*)d_in[1];
  const float* conv1_w  = (const float*)d_in[2];
  const float* conv1_b  = (const float*)d_in[3];
  const float* conv2_w  = (const float*)d_in[4];
  const float* g_diff   = (const float*)d_in[5];
  const float* g_res    = (const float*)d_in[6];
  const float* g2       = (const float*)d_in[7];
  const float* g3       = (const float*)d_in[8];
  const float* qkv2_w   = (const float*)d_in[9];
  const float* qkv2_b   = (const float*)d_in[10];
  const float* out2_w   = (const float*)d_in[11];
  const float* qkv3_w   = (const float*)d_in[12];
  const float* qkv3_b   = (const float*)d_in[13];
  const float* out3_w   = (const float*)d_in[14];
  const float* lsa_qkv_w = (const float*)d_in[15];
  const float* lsa_out_w = (const float*)d_in[16];
  float* out = (float*)d_out;
  float* ws = (float*)d_ws;

  // ws layout (~26.5M floats = 101 MB)
  float* W     = ws;                                   // NN
  float* Qch   = ws + (size_t)NN;                      // 8192*768
  float* Ych   = Qch + (size_t)CH_ROWS * 768;          // 8192*256
  float* WT1   = Ych + (size_t)CH_ROWS * 256;          // 589824
  float* WT2   = WT1 + 589824;                         // 589824
  float* Y3    = WT2 + 589824;                         // 65536
  float* Y3O   = Y3 + 65536;                           // 65536
  float* Y3N   = Y3O + 65536;                          // 65536
  float* STATS = Y3N + 65536;                          // 256
  float* D     = out;                                  // d_out as NN scratch until final stage

  dim3 b256(256);
  transpose_w_k<<<2304, b256, 0, stream>>>(conv1_w, WT1);
  transpose_w_k<<<2304, b256, 0, stream>>>(conv2_w, WT2);

  // ---- residual block ----
  zero_stats_k<<<1, b256, 0, stream>>>(STATS);
  gn_stats_contig<<<1024, b256, 0, stream>>>(x, STATS);
  gn_apply_contig<<<16384, b256, 0, stream>>>(x, STATS, D, 1e-6f, nullptr, nullptr);
  conv3x3_k<<<dim3(4, 64, 16), b256, 0, stream>>>(D, WT1, conv1_b, temb, g_diff, W, 1);
  zero_stats_k<<<1, b256, 0, stream>>>(STATS);
  gn_stats_contig<<<1024, b256, 0, stream>>>(W, STATS);
  gn_apply_contig<<<16384, b256, 0, stream>>>(W, STATS, D, 1e-6f, nullptr, nullptr);
  conv3x3_k<<<dim3(4, 64, 16), b256, 0, stream>>>(D, WT2, nullptr, nullptr, nullptr, W, 0);
  zero_stats_k<<<1, b256, 0, stream>>>(STATS);
  gn_stats_contig<<<1024, b256, 0, stream>>>(W, STATS);
  gn_apply_contig<<<16384, b256, 0, stream>>>(W, STATS, W, 1e-6f, x, g_res);   // W = x1

  // ---- layer2: freq attention (xf lives in D) ----
  x1_to_xf_k<<<16384, b256, 0, stream>>>(W, D);
  for (int c = 0; c < NCH; ++c) {
    float* Arows = D + (size_t)c * CH_ROWS * 256;
    gemm_k<<<dim3(12, 128), b256, 0, stream>>>(Arows, 256, qkv2_w, 768, qkv2_b, Qch, 768, nullptr, 0, 0.f);
    attn2_k<<<1024, b256, 0, stream>>>(Qch);
    gemm_k<<<dim3(4, 128), b256, 0, stream>>>(Qch, 768, out2_w, 256, nullptr, Ych, 256, nullptr, 0, 0.f);
    gn_rows_add_k<<<1024, b256, 0, stream>>>(Ych, Arows, g2);
  }

  // ---- layer3: global time attention (xt lives in W) ----
  xf_to_xt_k<<<16384, b256, 0, stream>>>(D, W);
  for (int c = 0; c < NCH; ++c) {
    const float* Arows = W + (size_t)c * CH_ROWS * 256;
    gemm_k<<<dim3(12, 128), b256, 0, stream>>>(Arows, 256, qkv3_w, 768, qkv3_b, Qch, 768, nullptr, 0, 0.f);
    attn3_k<<<256, b256, 0, stream>>>(Qch, Y3, c * 32);
  }
  gemm_k<<<dim3(4, 4), b256, 0, stream>>>(Y3, 256, out3_w, 256, nullptr, Y3O, 256, nullptr, 0, 0.f);
  gn_rows_k<<<32, b256, 0, stream>>>(Y3O, Y3N, 256 * 32);
  bcast_add_k<<<16384, b256, 0, stream>>>(W, Y3N, g3);

  // ---- layer4: LSA (gn fused into qkv gemm A-load; o in-place in Qch; out = d_out) ----
  zero_stats_k<<<1, b256, 0, stream>>>(STATS);
  gn_stats_xt_k<<<8192, b256, 0, stream>>>(W, STATS);
  for (int c = 0; c < NCH; ++c) {
    const float* Arows = W + (size_t)c * CH_ROWS * 256;
    gemm_k<<<dim3(12, 128), b256, 0, stream>>>(Arows, 256, lsa_qkv_w, 768, nullptr, Qch, 768,
                                               STATS, c * CH_ROWS, 1e-5f);
    lsa_attn_k<<<512, b256, 0, stream>>>(Qch);
    gemm_k<<<dim3(4, 128), b256, 0, stream>>>(Qch, 768, lsa_out_w, 256, nullptr, Ych, 256, nullptr, 0, 0.f);
    final_out_k<<<2048, b256, 0, stream>>>(W, Ych, out, c * 32);
  }
}

// Round 3
// 2079.404 us; speedup vs baseline: 2.5794x; 2.5794x over previous
//
#include <hip/hip_runtime.h>

#define NN 16777216   // 4*256*64*256
#define CC 256
#define FF 64
#define TT 256
#define CH_ROWS 8192
#define NCH 8

typedef short v8s __attribute__((ext_vector_type(8)));
typedef float v4f __attribute__((ext_vector_type(4)));

__device__ __forceinline__ unsigned short f2bf(float f) {
  unsigned u = __float_as_uint(f);
  u += 0x7fff + ((u >> 16) & 1);
  return (unsigned short)(u >> 16);
}

// ---------------- helpers ----------------
__device__ __forceinline__ void blockReduce2(float& a, float& b, float* sbuf) {
  #pragma unroll
  for (int off = 32; off > 0; off >>= 1) {
    a += __shfl_down(a, off, 64);
    b += __shfl_down(b, off, 64);
  }
  int w = threadIdx.x >> 6;
  if ((threadIdx.x & 63) == 0) { sbuf[w] = a; sbuf[4 + w] = b; }
  __syncthreads();
  if (threadIdx.x == 0) {
    a = sbuf[0] + sbuf[1] + sbuf[2] + sbuf[3];
    b = sbuf[4] + sbuf[5] + sbuf[6] + sbuf[7];
  }
}

__global__ void zero_stats_k(float* p) { p[threadIdx.x] = 0.f; }

// ---------------- weight prep ----------------
// conv w [co][ci][3][3] fp32 -> wb [tap][co][ci] bf16
__global__ void convw_bf_k(const float* __restrict__ w, unsigned short* __restrict__ wb) {
  int s = blockIdx.x * 256 + threadIdx.x;
  if (s < 589824) {
    int co = s / 2304, r = s % 2304;
    int ci = r / 9, tap = r % 9;
    wb[(tap * 256 + co) * 256 + ci] = f2bf(w[s]);
  }
}

// W [K=256][N] fp32 -> BT [n][k] bf16
__global__ void matT_bf_k(const float* __restrict__ w, unsigned short* __restrict__ bt, int N, int total) {
  int s = blockIdx.x * 256 + threadIdx.x;
  if (s < total) {
    int k = s / N, n = s % N;
    bt[n * 256 + k] = f2bf(w[s]);
  }
}

// ---------------- GroupNorm (NCHW contiguous groups: 131072 elems/group) ----------------
__global__ __launch_bounds__(256) void gn_stats_contig(const float* __restrict__ src, float* __restrict__ stats) {
  __shared__ float sbuf[8];
  int grp = blockIdx.x >> 3, chunk = blockIdx.x & 7;
  const float4* p = (const float4*)src + grp * 32768 + chunk * 4096;
  float s = 0.f, ss = 0.f;
  for (int i = threadIdx.x; i < 4096; i += 256) {
    float4 v = p[i];
    s += v.x + v.y + v.z + v.w;
    ss += v.x * v.x + v.y * v.y + v.z * v.z + v.w * v.w;
  }
  blockReduce2(s, ss, sbuf);
  if (threadIdx.x == 0) { atomicAdd(&stats[grp], s); atomicAdd(&stats[128 + grp], ss); }
}

__global__ __launch_bounds__(256) void gn_apply_contig(const float* __restrict__ src, const float* __restrict__ stats,
    float* __restrict__ dst, float eps, const float* __restrict__ resid, const float* __restrict__ gate) {
  int i4 = blockIdx.x * 256 + threadIdx.x;
  int gi = i4 >> 15;
  float mean = stats[gi] * (1.f / 131072.f);
  float var = stats[128 + gi] * (1.f / 131072.f) - mean * mean;
  float r = rsqrtf(var + eps);
  float4 v = ((const float4*)src)[i4];
  float4 o;
  o.x = (v.x - mean) * r; o.y = (v.y - mean) * r; o.z = (v.z - mean) * r; o.w = (v.w - mean) * r;
  if (resid) {
    float g = gate[0];
    float4 x = ((const float4*)resid)[i4];
    o.x = x.x + g * o.x; o.y = x.y + g * o.y; o.z = x.z + g * o.z; o.w = x.w + g * o.w;
  }
  ((float4*)dst)[i4] = o;
}

// ---------------- conv 3x3 via MFMA (implicit GEMM) ----------------
// in fp32 [b][ci][f][t]; wb bf16 [tap][co][ci]; out fp32 [b][co][f][t]
// grid (2 t-halves, 64 f, 8 = b*2 + coHalf)
__global__ __launch_bounds__(256) void conv3x3_mfma_k(const float* __restrict__ in,
    const unsigned short* __restrict__ wb, const float* __restrict__ bias,
    const float* __restrict__ temb, const float* __restrict__ gd,
    float* __restrict__ out, int mode) {
  __shared__ __align__(16) unsigned short sIn[3][132][40];
  __shared__ __align__(16) unsigned short sW[128][40];
  int t0 = blockIdx.x * 128;
  int f  = blockIdx.y;
  int b  = blockIdx.z >> 1;
  int co0 = (blockIdx.z & 1) * 128;
  int tid = threadIdx.x;
  int wave = tid >> 6, lane = tid & 63;
  int lm = lane & 15, quad = lane >> 4;
  int w32 = wave * 32;
  v4f acc[2][8];
  #pragma unroll
  for (int i = 0; i < 2; ++i)
    #pragma unroll
    for (int j = 0; j < 8; ++j) acc[i][j] = (v4f)(0.f);

  for (int ci0 = 0; ci0 < 256; ci0 += 32) {
    __syncthreads();
    // stage input tile: [df][tl=1..128][ci 32] (2 ci per thread, packed b32 writes)
    for (int s = tid; s < 6144; s += 256) {
      int df = s >> 11, r = s & 2047;
      int ci2 = r >> 7, tt = r & 127;
      int fi = f + df - 1;
      int ci = ci0 + ci2 * 2;
      float v0 = 0.f, v1 = 0.f;
      if (fi >= 0 && fi < 64) {
        const float* p = &in[(((size_t)b * 256 + ci) * 64 + fi) * 256 + t0 + tt];
        v0 = p[0]; v1 = p[16384];
      }
      *(unsigned*)&sIn[df][1 + tt][ci2 * 2] = (unsigned)f2bf(v0) | ((unsigned)f2bf(v1) << 16);
    }
    // halo tl=0 and tl=129
    if (tid < 96) {
      int df = tid >> 5, r = tid & 31;
      int side = r >> 4, ci2 = r & 15;
      int tl = side ? 129 : 0;
      int ti = t0 - 1 + side * 129;
      int fi = f + df - 1;
      int ci = ci0 + ci2 * 2;
      float v0 = 0.f, v1 = 0.f;
      if (fi >= 0 && fi < 64 && ti >= 0 && ti < 256) {
        const float* p = &in[(((size_t)b * 256 + ci) * 64 + fi) * 256 + ti];
        v0 = p[0]; v1 = p[16384];
      }
      *(unsigned*)&sIn[df][tl][ci2 * 2] = (unsigned)f2bf(v0) | ((unsigned)f2bf(v1) << 16);
    }
    for (int tap = 0; tap < 9; ++tap) {
      __syncthreads();
      #pragma unroll
      for (int i = 0; i < 2; ++i) {
        int s = tid + i * 256;
        int co = s >> 2, part = s & 3;
        *(uint4*)&sW[co][part * 8] =
            *(const uint4*)&wb[((size_t)(tap * 256) + co0 + co) * 256 + ci0 + part * 8];
      }
      __syncthreads();
      int df = tap / 3;
      int dtm = tap - df * 3;
      v8s A0 = *(const v8s*)&sIn[df][w32 + lm + dtm][quad * 8];
      v8s A1 = *(const v8s*)&sIn[df][w32 + 16 + lm + dtm][quad * 8];
      #pragma unroll
      for (int nt = 0; nt < 8; ++nt) {
        v8s B = *(const v8s*)&sW[nt * 16 + lm][quad * 8];
        acc[0][nt] = __builtin_amdgcn_mfma_f32_16x16x32_bf16(A0, B, acc[0][nt], 0, 0, 0);
        acc[1][nt] = __builtin_amdgcn_mfma_f32_16x16x32_bf16(A1, B, acc[1][nt], 0, 0, 0);
      }
    }
  }
  float gdv = mode ? gd[0] : 0.f;
  #pragma unroll
  for (int nt = 0; nt < 8; ++nt) {
    int co = co0 + nt * 16 + lm;
    float bb = 0.f;
    if (mode) bb = bias[co] + gdv * temb[b * 256 + co];
    #pragma unroll
    for (int mt = 0; mt < 2; ++mt) {
      int t = t0 + w32 + mt * 16 + quad * 4;
      float4 o;
      float v0 = acc[mt][nt][0] + bb, v1 = acc[mt][nt][1] + bb;
      float v2 = acc[mt][nt][2] + bb, v3 = acc[mt][nt][3] + bb;
      if (mode) {
        v0 = v0 / (1.f + expf(-v0)); v1 = v1 / (1.f + expf(-v1));
        v2 = v2 / (1.f + expf(-v2)); v3 = v3 / (1.f + expf(-v3));
      }
      o.x = v0; o.y = v1; o.z = v2; o.w = v3;
      *(float4*)&out[(((size_t)b * 256 + co) * 64 + f) * 256 + t] = o;
    }
  }
}

// ---------------- MFMA GEMM: C[M,N] = gn?(A[M,256]) @ B[256,N] (+bias) ----------------
// BT bf16 [n][k]; grid (N/128, M/128)
__global__ __launch_bounds__(256) void gemm_mfma_k(const float* __restrict__ A, int lda,
    const unsigned short* __restrict__ BT, const float* __restrict__ bias,
    float* __restrict__ C, int ldc,
    const float* __restrict__ gstats, int growbase, float eps) {
  __shared__ __align__(16) unsigned short sA[128][40];
  __shared__ __align__(16) unsigned short sB[128][40];
  int n0 = blockIdx.x * 128, m0 = blockIdx.y * 128;
  int tid = threadIdx.x;
  int wave = tid >> 6, lane = tid & 63;
  int wm = wave >> 1, wn = wave & 1;
  int lm = lane & 15, quad = lane >> 4;
  v4f acc[4][4];
  #pragma unroll
  for (int i = 0; i < 4; ++i)
    #pragma unroll
    for (int j = 0; j < 4; ++j) acc[i][j] = (v4f)(0.f);

  for (int k0 = 0; k0 < 256; k0 += 32) {
    __syncthreads();
    #pragma unroll
    for (int i = 0; i < 4; ++i) {
      int s = tid + i * 256;
      int row = s >> 3, k4 = s & 7;
      float4 av = *(const float4*)&A[(size_t)(m0 + row) * lda + k0 + k4 * 4];
      if (gstats) {
        int grp = ((growbase + m0 + row) >> 14) * 32 + ((k0 + k4 * 4) >> 3);
        float mean = gstats[grp] * (1.f / 131072.f);
        float var = gstats[128 + grp] * (1.f / 131072.f) - mean * mean;
        float rr = rsqrtf(var + eps);
        av.x = (av.x - mean) * rr; av.y = (av.y - mean) * rr;
        av.z = (av.z - mean) * rr; av.w = (av.w - mean) * rr;
      }
      unsigned lo = (unsigned)f2bf(av.x) | ((unsigned)f2bf(av.y) << 16);
      unsigned hi = (unsigned)f2bf(av.z) | ((unsigned)f2bf(av.w) << 16);
      *(uint2*)&sA[row][k4 * 4] = make_uint2(lo, hi);
    }
    #pragma unroll
    for (int i = 0; i < 2; ++i) {
      int s = tid + i * 256;
      int n = s >> 2, part = s & 3;
      *(uint4*)&sB[n][part * 8] = *(const uint4*)&BT[(size_t)(n0 + n) * 256 + k0 + part * 8];
    }
    __syncthreads();
    v8s Af[4];
    #pragma unroll
    for (int mt = 0; mt < 4; ++mt)
      Af[mt] = *(const v8s*)&sA[wm * 64 + mt * 16 + lm][quad * 8];
    #pragma unroll
    for (int nt = 0; nt < 4; ++nt) {
      v8s Bf = *(const v8s*)&sB[wn * 64 + nt * 16 + lm][quad * 8];
      #pragma unroll
      for (int mt = 0; mt < 4; ++mt)
        acc[mt][nt] = __builtin_amdgcn_mfma_f32_16x16x32_bf16(Af[mt], Bf, acc[mt][nt], 0, 0, 0);
    }
  }
  #pragma unroll
  for (int nt = 0; nt < 4; ++nt) {
    int col = n0 + wn * 64 + nt * 16 + lm;
    float bb = bias ? bias[col] : 0.f;
    #pragma unroll
    for (int mt = 0; mt < 4; ++mt) {
      int row = m0 + wm * 64 + mt * 16 + quad * 4;
      #pragma unroll
      for (int r = 0; r < 4; ++r)
        C[(size_t)(row + r) * ldc + col] = acc[mt][nt][r] + bb;
    }
  }
}

// ---------------- fp32 GEMM (kept for the tiny 256x256 out3 matmul) ----------------
__global__ __launch_bounds__(256) void gemm_k(const float* __restrict__ A, int lda,
    const float* __restrict__ Bm, int N, const float* __restrict__ bias,
    float* __restrict__ Cm, int ldc) {
  __shared__ __align__(16) float sA[16][64];
  __shared__ __align__(16) float sB[16][64];
  int n0 = blockIdx.x * 64, m0 = blockIdx.y * 64;
  int tid = threadIdx.x;
  int tx = tid & 15, ty = tid >> 4;
  int arow = m0 + (tid >> 2), acol = (tid & 3) * 4;
  int brow = tid >> 4, bcol = (tid & 15) * 4;
  float acc[4][4] = {};
  for (int k0 = 0; k0 < 256; k0 += 16) {
    __syncthreads();
    float4 av = *(const float4*)&A[(size_t)arow * lda + k0 + acol];
    sA[acol + 0][tid >> 2] = av.x;
    sA[acol + 1][tid >> 2] = av.y;
    sA[acol + 2][tid >> 2] = av.z;
    sA[acol + 3][tid >> 2] = av.w;
    *(float4*)&sB[brow][bcol] = *(const float4*)&Bm[(k0 + brow) * N + n0 + bcol];
    __syncthreads();
    #pragma unroll
    for (int kk = 0; kk < 16; ++kk) {
      float4 a = *(const float4*)&sA[kk][ty * 4];
      float4 b = *(const float4*)&sB[kk][tx * 4];
      float aa[4] = {a.x, a.y, a.z, a.w};
      float bb[4] = {b.x, b.y, b.z, b.w};
      #pragma unroll
      for (int i = 0; i < 4; ++i)
        #pragma unroll
        for (int j = 0; j < 4; ++j)
          acc[i][j] += aa[i] * bb[j];
    }
  }
  #pragma unroll
  for (int i = 0; i < 4; ++i)
    #pragma unroll
    for (int j = 0; j < 4; ++j) {
      int n = n0 + tx * 4 + j;
      float v = acc[i][j];
      if (bias) v += bias[n];
      Cm[(size_t)(m0 + ty * 4 + i) * ldc + n] = v;
    }
}

// ---------------- transposes ----------------
__global__ __launch_bounds__(256) void x1_to_xf_k(const float* __restrict__ X1, float* __restrict__ XF) {
  __shared__ float sT[32][33];
  int bx = blockIdx.x;
  int r = bx >> 6;
  int c0 = ((bx >> 3) & 7) * 32;
  int t0 = (bx & 7) * 32;
  int b = r >> 6, f = r & 63;
  int tl = threadIdx.x & 31, tr = threadIdx.x >> 5;
  #pragma unroll
  for (int i = 0; i < 4; ++i) {
    int c = c0 + tr + i * 8;
    sT[tr + i * 8][tl] = X1[((b * CC + c) * FF + f) * TT + t0 + tl];
  }
  __syncthreads();
  #pragma unroll
  for (int i = 0; i < 4; ++i) {
    int t = t0 + tr + i * 8;
    XF[((b * TT + t) * FF + f) * CC + c0 + tl] = sT[tl][tr + i * 8];
  }
}

__global__ __launch_bounds__(256) void xf_to_xt_k(const float* __restrict__ XF, float* __restrict__ XT) {
  int rowid = blockIdx.x * 4 + (threadIdx.x >> 6);
  int lane = threadIdx.x & 63;
  int b = rowid >> 14, f = (rowid >> 8) & 63, t = rowid & 255;
  int src = ((b * TT + t) * FF + f) * CC + lane * 4;
  int dst = rowid * CC + lane * 4;
  *(float4*)&XT[dst] = *(const float4*)&XF[src];
}

__global__ __launch_bounds__(256) void final_out_k(const float* __restrict__ XT, const float* __restrict__ O2,
                                                   float* __restrict__ out, int rbase) {
  __shared__ float sT[32][33];
  int bx = blockIdx.x;
  int rl = bx >> 6;
  int t0 = ((bx >> 3) & 7) * 32;
  int c0 = (bx & 7) * 32;
  int rg = rbase + rl;
  int b = rg >> 6, f = rg & 63;
  int tc = threadIdx.x & 31, tr = threadIdx.x >> 5;
  #pragma unroll
  for (int i = 0; i < 4; ++i) {
    int t = t0 + tr + i * 8;
    sT[tr + i * 8][tc] = XT[rg * 65536 + t * 256 + c0 + tc] + O2[rl * 65536 + t * 256 + c0 + tc];
  }
  __syncthreads();
  #pragma unroll
  for (int i = 0; i < 4; ++i) {
    int c = c0 + tr + i * 8;
    out[((b * CC + c) * FF + f) * TT + t0 + tc] = sT[tc][tr + i * 8];
  }
}

// ---------------- attention: frequency axis (seq 64), in-place y -> q columns ----------------
__global__ __launch_bounds__(256) void attn2_k(float* __restrict__ Q) {
  __shared__ float sq[64][33], sk[64][33], sv[64][33];
  __shared__ float sS[64][65];
  __shared__ float sInv[64];
  int bt = blockIdx.x >> 3, h = blockIdx.x & 7;
  int tid = threadIdx.x;
  const float scale = 0.17677669529663687f;
  for (int s = tid; s < 2048; s += 256) {
    int fq = s >> 5, d = s & 31;
    int base = (bt * 64 + fq) * 768 + h * 32 + d;
    sq[fq][d] = Q[base];
    sk[fq][d] = Q[base + 256];
    sv[fq][d] = Q[base + 512];
  }
  __syncthreads();
  {
    int L = tid >> 2, lg = tid & 3;
    float a[16] = {};
    for (int d = 0; d < 32; ++d) {
      float qv = sq[L][d];
      #pragma unroll
      for (int j = 0; j < 16; ++j) a[j] += qv * sk[lg * 16 + j][d];
    }
    #pragma unroll
    for (int j = 0; j < 16; ++j) sS[L][lg * 16 + j] = a[j] * scale;
  }
  __syncthreads();
  if (tid < 64) {
    float mx = -1e30f;
    for (int l = 0; l < 64; ++l) mx = fmaxf(mx, sS[tid][l]);
    float sum = 0.f;
    for (int l = 0; l < 64; ++l) { float e = expf(sS[tid][l] - mx); sS[tid][l] = e; sum += e; }
    sInv[tid] = 1.f / sum;
  }
  __syncthreads();
  {
    int L = tid >> 2, dg = tid & 3;
    float a[8] = {};
    for (int l = 0; l < 64; ++l) {
      float p = sS[L][l];
      #pragma unroll
      for (int j = 0; j < 8; ++j) a[j] += p * sv[l][dg * 8 + j];
    }
    float r = sInv[L];
    #pragma unroll
    for (int j = 0; j < 8; ++j)
      Q[(bt * 64 + L) * 768 + h * 32 + dg * 8 + j] = a[j] * r;
  }
}

// ---------------- attention: global time (pooled q, seq 256) ----------------
__global__ __launch_bounds__(256) void attn3_k(const float* __restrict__ Q3, float* __restrict__ y3, int bf_base) {
  __shared__ float part[8][32];
  __shared__ float sqm[32];
  __shared__ float sp[256];
  __shared__ float sred[256];
  int bfl = blockIdx.x >> 3, h = blockIdx.x & 7;
  int tid = threadIdx.x;
  int tg = tid >> 5, d = tid & 31;
  const float scale = 0.17677669529663687f;
  int rowbase = bfl * 256;
  float s = 0.f;
  for (int t = tg * 32; t < tg * 32 + 32; ++t) s += Q3[(rowbase + t) * 768 + h * 32 + d];
  part[tg][d] = s;
  __syncthreads();
  if (tid < 32) {
    float m = 0.f;
    for (int g = 0; g < 8; ++g) m += part[g][tid];
    sqm[tid] = m * (1.f / 256.f);
  }
  __syncthreads();
  {
    float dot = 0.f;
    const float* kp = &Q3[(rowbase + tid) * 768 + 256 + h * 32];
    for (int dd = 0; dd < 32; ++dd) dot += sqm[dd] * kp[dd];
    sp[tid] = dot * scale;
    sred[tid] = sp[tid];
  }
  __syncthreads();
  for (int st = 128; st > 0; st >>= 1) { if (tid < st) sred[tid] = fmaxf(sred[tid], sred[tid + st]); __syncthreads(); }
  float mx = sred[0];
  __syncthreads();
  float e = expf(sp[tid] - mx);
  sred[tid] = e;
  __syncthreads();
  for (int st = 128; st > 0; st >>= 1) { if (tid < st) sred[tid] += sred[tid + st]; __syncthreads(); }
  float rinv = 1.f / sred[0];
  sp[tid] = e * rinv;
  __syncthreads();
  float acc = 0.f;
  for (int t = tg * 32; t < tg * 32 + 32; ++t) acc += sp[t] * Q3[(rowbase + t) * 768 + 512 + h * 32 + d];
  part[tg][d] = acc;
  __syncthreads();
  if (tid < 32) {
    float o = 0.f;
    for (int g = 0; g < 8; ++g) o += part[g][tid];
    y3[(bf_base + bfl) * 256 + h * 32 + tid] = o;
  }
}

// ---------------- LSA: local window 16 along T, in-place o -> q columns ----------------
__global__ __launch_bounds__(256) void lsa_attn_k(float* __restrict__ Q4) {
  __shared__ __align__(16) float sX[16][772];
  __shared__ float sS[8][16][17];
  __shared__ float sInv[8][16];
  int bfl = blockIdx.x >> 4, w = blockIdx.x & 15;
  int tid = threadIdx.x;
  int rb = (bfl * 256 + w * 16) * 768;
  for (int s = tid; s < 3072; s += 256) {
    int t = s / 192, c4 = s % 192;
    *(float4*)&sX[t][c4 * 4] = *(const float4*)&Q4[rb + t * 768 + c4 * 4];
  }
  __syncthreads();
  const float scale = 0.17677669529663687f;
  #pragma unroll
  for (int rep = 0; rep < 8; ++rep) {
    int idx = tid + rep * 256;
    int h = idx >> 8, q = (idx >> 4) & 15, k = idx & 15;
    float dot = 0.f;
    const float* qp = &sX[q][h * 32];
    const float* kp = &sX[k][256 + h * 32];
    for (int d = 0; d < 32; ++d) dot += qp[d] * kp[d];
    sS[h][q][k] = dot * scale;
  }
  __syncthreads();
  if (tid < 128) {
    int h = tid >> 4, q = tid & 15;
    float mx = -1e30f;
    for (int k = 0; k < 16; ++k) mx = fmaxf(mx, sS[h][q][k]);
    float sum = 0.f;
    for (int k = 0; k < 16; ++k) { float e = expf(sS[h][q][k] - mx); sS[h][q][k] = e; sum += e; }
    sInv[h][q] = 1.f / sum;
  }
  __syncthreads();
  #pragma unroll
  for (int rep = 0; rep < 16; ++rep) {
    int idx = tid + rep * 256;
    int t = idx >> 8, c = idx & 255;
    int h = c >> 5;
    float acc = 0.f;
    for (int k = 0; k < 16; ++k) acc += sS[h][t][k] * sX[k][512 + c];
    Q4[rb + t * 768 + c] = acc * sInv[h][t];
  }
}

// ---------------- per-row GroupNorm (8-ch groups), fused residual add ----------------
__global__ __launch_bounds__(256) void gn_rows_add_k(const float* __restrict__ y2, float* __restrict__ xf,
                                                     const float* __restrict__ gate) {
  int s = blockIdx.x * 256 + threadIdx.x;
  int base = s * 8;
  float4 a = *(const float4*)&y2[base];
  float4 b = *(const float4*)&y2[base + 4];
  float m = (a.x + a.y + a.z + a.w + b.x + b.y + b.z + b.w) * 0.125f;
  float q = (a.x * a.x + a.y * a.y + a.z * a.z + a.w * a.w +
             b.x * b.x + b.y * b.y + b.z * b.z + b.w * b.w) * 0.125f - m * m;
  float r = rsqrtf(q + 1e-5f);
  float g = gate[0];
  float4 xa = *(const float4*)&xf[base];
  float4 xb = *(const float4*)&xf[base + 4];
  xa.x += g * (a.x - m) * r; xa.y += g * (a.y - m) * r; xa.z += g * (a.z - m) * r; xa.w += g * (a.w - m) * r;
  xb.x += g * (b.x - m) * r; xb.y += g * (b.y - m) * r; xb.z += g * (b.z - m) * r; xb.w += g * (b.w - m) * r;
  *(float4*)&xf[base] = xa;
  *(float4*)&xf[base + 4] = xb;
}

__global__ void gn_rows_k(const float* __restrict__ src, float* __restrict__ dst, int total) {
  int s = blockIdx.x * 256 + threadIdx.x;
  if (s >= total) return;
  int base = s * 8;
  float4 a = *(const float4*)&src[base];
  float4 b = *(const float4*)&src[base + 4];
  float m = (a.x + a.y + a.z + a.w + b.x + b.y + b.z + b.w) * 0.125f;
  float q = (a.x * a.x + a.y * a.y + a.z * a.z + a.w * a.w +
             b.x * b.x + b.y * b.y + b.z * b.z + b.w * b.w) * 0.125f - m * m;
  float r = rsqrtf(q + 1e-5f);
  a.x = (a.x - m) * r; a.y = (a.y - m) * r; a.z = (a.z - m) * r; a.w = (a.w - m) * r;
  b.x = (b.x - m) * r; b.y = (b.y - m) * r; b.z = (b.z - m) * r; b.w = (b.w - m) * r;
  *(float4*)&dst[base] = a;
  *(float4*)&dst[base + 4] = b;
}

__global__ __launch_bounds__(256) void bcast_add_k(float* __restrict__ XT, const float* __restrict__ y3n,
                                                   const float* __restrict__ gate) {
  int i4 = blockIdx.x * 256 + threadIdx.x;
  int flat = i4 * 4;
  int r = flat >> 16, c = flat & 255;
  float g = gate[0];
  float4 v = ((float4*)XT)[i4];
  float4 a = *(const float4*)&y3n[r * 256 + c];
  v.x += g * a.x; v.y += g * a.y; v.z += g * a.z; v.w += g * a.w;
  ((float4*)XT)[i4] = v;
}

// ---------------- GroupNorm stats over XT layout [bf][t][c] per (b, g) ----------------
__global__ __launch_bounds__(256) void gn_stats_xt_k(const float* __restrict__ X, float* __restrict__ stats) {
  __shared__ float sbuf[8];
  int bx = blockIdx.x;
  int b = bx >> 11, g = (bx >> 6) & 31, f = bx & 63;
  int base = (b * 64 + f) * 65536 + g * 8;
  float s = 0.f, ss = 0.f;
  for (int i = threadIdx.x; i < 2048; i += 256) {
    int t = i >> 3, c = i & 7;
    float v = X[base + t * 256 + c];
    s += v; ss += v * v;
  }
  blockReduce2(s, ss, sbuf);
  if (threadIdx.x == 0) { atomicAdd(&stats[b * 32 + g], s); atomicAdd(&stats[128 + b * 32 + g], ss); }
}

// ---------------- launch ----------------
extern "C" void kernel_launch(void* const* d_in, const int* in_sizes, int n_in,
                              void* d_out, int out_size, void* d_ws, size_t ws_size,
                              hipStream_t stream) {
  (void)in_sizes; (void)n_in; (void)out_size; (void)ws_size;
  const float* x        = (const float*)d_in[0];
  const float* temb     = (const float*)d_in[1];
  const float* conv1_w  = (const float*)d_in[2];
  const float* conv1_b  = (const float*)d_in[3];
  const float* conv2_w  = (const float*)d_in[4];
  const float* g_diff   = (const float*)d_in[5];
  const float* g_res    = (const float*)d_in[6];
  const float* g2       = (const float*)d_in[7];
  const float* g3       = (const float*)d_in[8];
  const float* qkv2_w   = (const float*)d_in[9];
  const float* qkv2_b   = (const float*)d_in[10];
  const float* out2_w   = (const float*)d_in[11];
  const float* qkv3_w   = (const float*)d_in[12];
  const float* qkv3_b   = (const float*)d_in[13];
  const float* out3_w   = (const float*)d_in[14];
  const float* lsa_qkv_w = (const float*)d_in[15];
  const float* lsa_out_w = (const float*)d_in[16];
  float* out = (float*)d_out;
  float* ws = (float*)d_ws;

  float* W     = ws;                                   // NN
  float* Qch   = ws + (size_t)NN;                      // 8192*768
  float* Ych   = Qch + (size_t)CH_ROWS * 768;          // 8192*256
  float* Y3    = Ych + (size_t)CH_ROWS * 256;          // 65536
  float* Y3O   = Y3 + 65536;
  float* Y3N   = Y3O + 65536;
  float* STATS = Y3N + 65536;                          // 256
  unsigned short* WB1   = (unsigned short*)(STATS + 256);   // 589824 bf16
  unsigned short* WB2   = WB1 + 589824;
  unsigned short* QKV2T = WB2 + 589824;                // 196608
  unsigned short* OUT2T = QKV2T + 196608;              // 65536
  unsigned short* QKV3T = OUT2T + 65536;               // 196608
  unsigned short* LSAQT = QKV3T + 196608;              // 196608
  unsigned short* LSAOT = LSAQT + 196608;              // 65536
  float* D     = out;                                  // d_out as NN scratch until final stage

  dim3 b256(256);
  convw_bf_k<<<2304, b256, 0, stream>>>(conv1_w, WB1);
  convw_bf_k<<<2304, b256, 0, stream>>>(conv2_w, WB2);
  matT_bf_k<<<768, b256, 0, stream>>>(qkv2_w, QKV2T, 768, 196608);
  matT_bf_k<<<256, b256, 0, stream>>>(out2_w, OUT2T, 256, 65536);
  matT_bf_k<<<768, b256, 0, stream>>>(qkv3_w, QKV3T, 768, 196608);
  matT_bf_k<<<768, b256, 0, stream>>>(lsa_qkv_w, LSAQT, 768, 196608);
  matT_bf_k<<<256, b256, 0, stream>>>(lsa_out_w, LSAOT, 256, 65536);

  // ---- residual block ----
  zero_stats_k<<<1, b256, 0, stream>>>(STATS);
  gn_stats_contig<<<1024, b256, 0, stream>>>(x, STATS);
  gn_apply_contig<<<16384, b256, 0, stream>>>(x, STATS, D, 1e-6f, nullptr, nullptr);
  conv3x3_mfma_k<<<dim3(2, 64, 8), b256, 0, stream>>>(D, WB1, conv1_b, temb, g_diff, W, 1);
  zero_stats_k<<<1, b256, 0, stream>>>(STATS);
  gn_stats_contig<<<1024, b256, 0, stream>>>(W, STATS);
  gn_apply_contig<<<16384, b256, 0, stream>>>(W, STATS, D, 1e-6f, nullptr, nullptr);
  conv3x3_mfma_k<<<dim3(2, 64, 8), b256, 0, stream>>>(D, WB2, nullptr, nullptr, nullptr, W, 0);
  zero_stats_k<<<1, b256, 0, stream>>>(STATS);
  gn_stats_contig<<<1024, b256, 0, stream>>>(W, STATS);
  gn_apply_contig<<<16384, b256, 0, stream>>>(W, STATS, W, 1e-6f, x, g_res);   // W = x1

  // ---- layer2: freq attention (xf lives in D) ----
  x1_to_xf_k<<<16384, b256, 0, stream>>>(W, D);
  for (int c = 0; c < NCH; ++c) {
    float* Arows = D + (size_t)c * CH_ROWS * 256;
    gemm_mfma_k<<<dim3(6, 64), b256, 0, stream>>>(Arows, 256, QKV2T, qkv2_b, Qch, 768, nullptr, 0, 0.f);
    attn2_k<<<1024, b256, 0, stream>>>(Qch);
    gemm_mfma_k<<<dim3(2, 64), b256, 0, stream>>>(Qch, 768, OUT2T, nullptr, Ych, 256, nullptr, 0, 0.f);
    gn_rows_add_k<<<1024, b256, 0, stream>>>(Ych, Arows, g2);
  }

  // ---- layer3: global time attention (xt lives in W) ----
  xf_to_xt_k<<<16384, b256, 0, stream>>>(D, W);
  for (int c = 0; c < NCH; ++c) {
    const float* Arows = W + (size_t)c * CH_ROWS * 256;
    gemm_mfma_k<<<dim3(6, 64), b256, 0, stream>>>(Arows, 256, QKV3T, qkv3_b, Qch, 768, nullptr, 0, 0.f);
    attn3_k<<<256, b256, 0, stream>>>(Qch, Y3, c * 32);
  }
  gemm_k<<<dim3(4, 4), b256, 0, stream>>>(Y3, 256, out3_w, 256, nullptr, Y3O, 256);
  gn_rows_k<<<32, b256, 0, stream>>>(Y3O, Y3N, 256 * 32);
  bcast_add_k<<<16384, b256, 0, stream>>>(W, Y3N, g3);

  // ---- layer4: LSA (gn fused into qkv gemm A-load) ----
  zero_stats_k<<<1, b256, 0, stream>>>(STATS);
  gn_stats_xt_k<<<8192, b256, 0, stream>>>(W, STATS);
  for (int c = 0; c < NCH; ++c) {
    const float* Arows = W + (size_t)c * CH_ROWS * 256;
    gemm_mfma_k<<<dim3(6, 64), b256, 0, stream>>>(Arows, 256, LSAQT, nullptr, Qch, 768,
                                                  STATS, c * CH_ROWS, 1e-5f);
    lsa_attn_k<<<512, b256, 0, stream>>>(Qch);
    gemm_mfma_k<<<dim3(2, 64), b256, 0, stream>>>(Qch, 768, LSAOT, nullptr, Ych, 256, nullptr, 0, 0.f);
    final_out_k<<<2048, b256, 0, stream>>>(W, Ych, out, c * 32);
  }
}

// Round 4
// 1267.643 us; speedup vs baseline: 4.2311x; 1.6404x over previous
//
#include <hip/hip_runtime.h>

#define NN 16777216   // 4*256*64*256
#define CC 256
#define FF 64
#define TT 256

typedef short v8s __attribute__((ext_vector_type(8)));
typedef float v4f __attribute__((ext_vector_type(4)));

__device__ __forceinline__ unsigned short f2bf(float f) {
  unsigned u = __float_as_uint(f);
  u += 0x7fff + ((u >> 16) & 1);
  return (unsigned short)(u >> 16);
}
__device__ __forceinline__ float bf2f(unsigned short h) {
  return __uint_as_float(((unsigned)h) << 16);
}
__device__ __forceinline__ unsigned packbf2(float a, float b) {
  return (unsigned)f2bf(a) | ((unsigned)f2bf(b) << 16);
}
__device__ __forceinline__ void unpack8(uint4 u, float* d) {
  d[0] = __uint_as_float(u.x << 16); d[1] = __uint_as_float(u.x & 0xffff0000u);
  d[2] = __uint_as_float(u.y << 16); d[3] = __uint_as_float(u.y & 0xffff0000u);
  d[4] = __uint_as_float(u.z << 16); d[5] = __uint_as_float(u.z & 0xffff0000u);
  d[6] = __uint_as_float(u.w << 16); d[7] = __uint_as_float(u.w & 0xffff0000u);
}

// ---------------- helpers ----------------
__device__ __forceinline__ void blockReduce2(float& a, float& b, float* sbuf) {
  #pragma unroll
  for (int off = 32; off > 0; off >>= 1) {
    a += __shfl_down(a, off, 64);
    b += __shfl_down(b, off, 64);
  }
  int w = threadIdx.x >> 6;
  if ((threadIdx.x & 63) == 0) { sbuf[w] = a; sbuf[4 + w] = b; }
  __syncthreads();
  if (threadIdx.x == 0) {
    a = sbuf[0] + sbuf[1] + sbuf[2] + sbuf[3];
    b = sbuf[4] + sbuf[5] + sbuf[6] + sbuf[7];
  }
}

__global__ void zero_stats_k(float* p) { p[threadIdx.x] = 0.f; }

// ---------------- weight prep ----------------
__global__ void convw_bf_k(const float* __restrict__ w, unsigned short* __restrict__ wb) {
  int s = blockIdx.x * 256 + threadIdx.x;
  if (s < 589824) {
    int co = s / 2304, r = s % 2304;
    int ci = r / 9, tap = r % 9;
    wb[(tap * 256 + co) * 256 + ci] = f2bf(w[s]);
  }
}

__global__ void matT_bf_k(const float* __restrict__ w, unsigned short* __restrict__ bt, int N, int total) {
  int s = blockIdx.x * 256 + threadIdx.x;
  if (s < total) {
    int k = s / N, n = s % N;
    bt[n * 256 + k] = f2bf(w[s]);
  }
}

// ---------------- GroupNorm stats (NCHW contiguous: 131072/group) ----------------
__global__ __launch_bounds__(256) void gn_stats_contig(const float* __restrict__ src, float* __restrict__ stats) {
  __shared__ float sbuf[8];
  int grp = blockIdx.x >> 3, chunk = blockIdx.x & 7;
  const float4* p = (const float4*)src + grp * 32768 + chunk * 4096;
  float s = 0.f, ss = 0.f;
  for (int i = threadIdx.x; i < 4096; i += 256) {
    float4 v = p[i];
    s += v.x + v.y + v.z + v.w;
    ss += v.x * v.x + v.y * v.y + v.z * v.z + v.w * v.w;
  }
  blockReduce2(s, ss, sbuf);
  if (threadIdx.x == 0) { atomicAdd(&stats[grp], s); atomicAdd(&stats[128 + grp], ss); }
}

// GN apply + transpose to bf16 [b][f][t][ci]
__global__ __launch_bounds__(256) void gn_apply_tr_k(const float* __restrict__ src,
    const float* __restrict__ stats, unsigned short* __restrict__ XC, float eps) {
  __shared__ float sT[32][33];
  int bx = blockIdx.x;
  int r = bx >> 6;
  int c0 = ((bx >> 3) & 7) * 32;
  int t0 = (bx & 7) * 32;
  int b = r >> 6, f = r & 63;
  int tl = threadIdx.x & 31, tr = threadIdx.x >> 5;
  #pragma unroll
  for (int i = 0; i < 4; ++i) {
    int c = c0 + tr + i * 8;
    int grp = b * 32 + (c >> 3);
    float mean = stats[grp] * (1.f / 131072.f);
    float var = stats[128 + grp] * (1.f / 131072.f) - mean * mean;
    float rv = rsqrtf(var + eps);
    float v = src[((b * 256 + c) * 64 + f) * 256 + t0 + tl];
    sT[tr + i * 8][tl] = (v - mean) * rv;
  }
  __syncthreads();
  #pragma unroll
  for (int i = 0; i < 4; ++i) {
    int t = t0 + tr + i * 8;
    XC[(((size_t)(b * 64 + f)) * 256 + t) * 256 + c0 + tl] = f2bf(sT[tl][tr + i * 8]);
  }
}

// GN apply + gated residual + transpose to XF fp32 [(b*256+t)*64+f][c]
__global__ __launch_bounds__(256) void gn_tr_resid_k(const float* __restrict__ h,
    const float* __restrict__ x, const float* __restrict__ stats,
    const float* __restrict__ gate, float* __restrict__ XF, float eps) {
  __shared__ float sT[32][33];
  int bx = blockIdx.x;
  int r = bx >> 6;
  int c0 = ((bx >> 3) & 7) * 32;
  int t0 = (bx & 7) * 32;
  int b = r >> 6, f = r & 63;
  int tl = threadIdx.x & 31, tr = threadIdx.x >> 5;
  float g = gate[0];
  #pragma unroll
  for (int i = 0; i < 4; ++i) {
    int c = c0 + tr + i * 8;
    int grp = b * 32 + (c >> 3);
    float mean = stats[grp] * (1.f / 131072.f);
    float var = stats[128 + grp] * (1.f / 131072.f) - mean * mean;
    float rv = rsqrtf(var + eps);
    int idx = ((b * 256 + c) * 64 + f) * 256 + t0 + tl;
    sT[tr + i * 8][tl] = x[idx] + g * (h[idx] - mean) * rv;
  }
  __syncthreads();
  #pragma unroll
  for (int i = 0; i < 4; ++i) {
    int t = t0 + tr + i * 8;
    XF[(((size_t)(b * 256 + t)) * 64 + f) * 256 + c0 + tl] = sT[tl][tr + i * 8];
  }
}

// ---------------- conv 3x3 via MFMA (implicit GEMM, bf16 pre-transposed input) ----------------
// XC bf16 [b][f][t][ci]; wb bf16 [tap][co][ci]; out fp32 [b][co][f][t]
// grid (64 f, 8 = b*2 + coHalf); block handles all 256 t x 128 co
__global__ __launch_bounds__(256, 2) void conv3x3_mfma_k(const unsigned short* __restrict__ XC,
    const unsigned short* __restrict__ wb, const float* __restrict__ bias,
    const float* __restrict__ temb, const float* __restrict__ gd,
    float* __restrict__ out, int mode) {
  __shared__ __align__(16) unsigned short sIn[3][258][40];
  __shared__ __align__(16) unsigned short sW[128][40];
  int f  = blockIdx.x;
  int b  = blockIdx.y >> 1;
  int co0 = (blockIdx.y & 1) * 128;
  int tid = threadIdx.x;
  int wave = tid >> 6, lane = tid & 63;
  int lm = lane & 15, quad = lane >> 4;
  int w64 = wave * 64;
  v4f acc[4][8];
  #pragma unroll
  for (int i = 0; i < 4; ++i)
    #pragma unroll
    for (int j = 0; j < 8; ++j) acc[i][j] = (v4f)(0.f);

  for (int ci0 = 0; ci0 < 256; ci0 += 32) {
    __syncthreads();
    for (int s = tid; s < 3096; s += 256) {
      int df = s / 1032, r = s - df * 1032;
      int tl = r >> 2, part = r & 3;
      int fi = f + df - 1, tg = tl - 1;
      uint4 val = make_uint4(0, 0, 0, 0);
      if (fi >= 0 && fi < 64 && tg >= 0 && tg < 256)
        val = *(const uint4*)&XC[(((size_t)(b * 64 + fi)) * 256 + tg) * 256 + ci0 + part * 8];
      *(uint4*)&sIn[df][tl][part * 8] = val;
    }
    for (int tap = 0; tap < 9; ++tap) {
      __syncthreads();
      {
        int co = tid >> 2, part = tid & 3;
        *(uint4*)&sW[co][part * 8] =
            *(const uint4*)&wb[((size_t)(tap * 256) + co0 + co) * 256 + ci0 + part * 8];
        int s1 = tid + 256;
        co = s1 >> 2; part = s1 & 3;
        *(uint4*)&sW[co][part * 8] =
            *(const uint4*)&wb[((size_t)(tap * 256) + co0 + co) * 256 + ci0 + part * 8];
      }
      __syncthreads();
      int df = tap / 3, dt = tap - df * 3;
      v8s A[4];
      #pragma unroll
      for (int mt = 0; mt < 4; ++mt)
        A[mt] = *(const v8s*)&sIn[df][w64 + mt * 16 + lm + dt][quad * 8];
      #pragma unroll
      for (int nt = 0; nt < 8; ++nt) {
        v8s B = *(const v8s*)&sW[nt * 16 + lm][quad * 8];
        #pragma unroll
        for (int mt = 0; mt < 4; ++mt)
          acc[mt][nt] = __builtin_amdgcn_mfma_f32_16x16x32_bf16(A[mt], B, acc[mt][nt], 0, 0, 0);
      }
    }
  }
  float gdv = mode ? gd[0] : 0.f;
  #pragma unroll
  for (int nt = 0; nt < 8; ++nt) {
    int co = co0 + nt * 16 + lm;
    float bb = 0.f;
    if (mode) bb = bias[co] + gdv * temb[b * 256 + co];
    #pragma unroll
    for (int mt = 0; mt < 4; ++mt) {
      int t = w64 + mt * 16 + quad * 4;
      float v0 = acc[mt][nt][0] + bb, v1 = acc[mt][nt][1] + bb;
      float v2 = acc[mt][nt][2] + bb, v3 = acc[mt][nt][3] + bb;
      if (mode) {
        v0 = v0 / (1.f + expf(-v0)); v1 = v1 / (1.f + expf(-v1));
        v2 = v2 / (1.f + expf(-v2)); v3 = v3 / (1.f + expf(-v3));
      }
      float4 o; o.x = v0; o.y = v1; o.z = v2; o.w = v3;
      *(float4*)&out[(((size_t)b * 256 + co) * 64 + f) * 256 + t] = o;
    }
  }
}

// ---------------- MFMA GEMM: Cb bf16 [M,N] = gn?(A fp32 [M,256]) @ B (+bias) ----------------
__global__ __launch_bounds__(256) void gemm_af32_k(const float* __restrict__ A, int lda,
    const unsigned short* __restrict__ BT, const float* __restrict__ bias,
    unsigned short* __restrict__ Cb, int ldc,
    const float* __restrict__ gstats, int growbase, float eps) {
  __shared__ __align__(16) unsigned short sA[128][40];
  __shared__ __align__(16) unsigned short sB[128][40];
  int n0 = blockIdx.x * 128, m0 = blockIdx.y * 128;
  int tid = threadIdx.x;
  int wave = tid >> 6, lane = tid & 63;
  int wm = wave >> 1, wn = wave & 1;
  int lm = lane & 15, quad = lane >> 4;
  v4f acc[4][4];
  #pragma unroll
  for (int i = 0; i < 4; ++i)
    #pragma unroll
    for (int j = 0; j < 4; ++j) acc[i][j] = (v4f)(0.f);

  for (int k0 = 0; k0 < 256; k0 += 32) {
    __syncthreads();
    #pragma unroll
    for (int i = 0; i < 4; ++i) {
      int s = tid + i * 256;
      int row = s >> 3, k4 = s & 7;
      float4 av = *(const float4*)&A[(size_t)(m0 + row) * lda + k0 + k4 * 4];
      if (gstats) {
        int grp = ((growbase + m0 + row) >> 14) * 32 + ((k0 + k4 * 4) >> 3);
        float mean = gstats[grp] * (1.f / 131072.f);
        float var = gstats[128 + grp] * (1.f / 131072.f) - mean * mean;
        float rr = rsqrtf(var + eps);
        av.x = (av.x - mean) * rr; av.y = (av.y - mean) * rr;
        av.z = (av.z - mean) * rr; av.w = (av.w - mean) * rr;
      }
      *(uint2*)&sA[row][k4 * 4] = make_uint2(packbf2(av.x, av.y), packbf2(av.z, av.w));
    }
    #pragma unroll
    for (int i = 0; i < 2; ++i) {
      int s = tid + i * 256;
      int n = s >> 2, part = s & 3;
      *(uint4*)&sB[n][part * 8] = *(const uint4*)&BT[(size_t)(n0 + n) * 256 + k0 + part * 8];
    }
    __syncthreads();
    v8s Af[4];
    #pragma unroll
    for (int mt = 0; mt < 4; ++mt)
      Af[mt] = *(const v8s*)&sA[wm * 64 + mt * 16 + lm][quad * 8];
    #pragma unroll
    for (int nt = 0; nt < 4; ++nt) {
      v8s Bf = *(const v8s*)&sB[wn * 64 + nt * 16 + lm][quad * 8];
      #pragma unroll
      for (int mt = 0; mt < 4; ++mt)
        acc[mt][nt] = __builtin_amdgcn_mfma_f32_16x16x32_bf16(Af[mt], Bf, acc[mt][nt], 0, 0, 0);
    }
  }
  #pragma unroll
  for (int nt = 0; nt < 4; ++nt) {
    int col = n0 + wn * 64 + nt * 16 + lm;
    float bb = bias ? bias[col] : 0.f;
    #pragma unroll
    for (int mt = 0; mt < 4; ++mt) {
      int row = m0 + wm * 64 + mt * 16 + quad * 4;
      #pragma unroll
      for (int r = 0; r < 4; ++r)
        Cb[(size_t)(row + r) * ldc + col] = f2bf(acc[mt][nt][r] + bb);
    }
  }
}

// ---------------- MFMA GEMM, A bf16: either bf16 C out, or fused rowGN+gate+add into xf ----------------
__global__ __launch_bounds__(256) void gemm_abf16_k(const unsigned short* __restrict__ A, int lda,
    const unsigned short* __restrict__ BT, float* __restrict__ xf,
    unsigned short* __restrict__ Cb, int ldc, const float* __restrict__ gate) {
  __shared__ __align__(16) unsigned short sA[128][40];
  __shared__ __align__(16) unsigned short sB[128][40];
  int n0 = blockIdx.x * 128, m0 = blockIdx.y * 128;
  int tid = threadIdx.x;
  int wave = tid >> 6, lane = tid & 63;
  int wm = wave >> 1, wn = wave & 1;
  int lm = lane & 15, quad = lane >> 4;
  v4f acc[4][4];
  #pragma unroll
  for (int i = 0; i < 4; ++i)
    #pragma unroll
    for (int j = 0; j < 4; ++j) acc[i][j] = (v4f)(0.f);

  for (int k0 = 0; k0 < 256; k0 += 32) {
    __syncthreads();
    #pragma unroll
    for (int i = 0; i < 2; ++i) {
      int s = tid + i * 256;
      int row = s >> 2, part = s & 3;
      *(uint4*)&sA[row][part * 8] = *(const uint4*)&A[(size_t)(m0 + row) * lda + k0 + part * 8];
      *(uint4*)&sB[row][part * 8] = *(const uint4*)&BT[(size_t)(n0 + row) * 256 + k0 + part * 8];
    }
    __syncthreads();
    v8s Af[4];
    #pragma unroll
    for (int mt = 0; mt < 4; ++mt)
      Af[mt] = *(const v8s*)&sA[wm * 64 + mt * 16 + lm][quad * 8];
    #pragma unroll
    for (int nt = 0; nt < 4; ++nt) {
      v8s Bf = *(const v8s*)&sB[wn * 64 + nt * 16 + lm][quad * 8];
      #pragma unroll
      for (int mt = 0; mt < 4; ++mt)
        acc[mt][nt] = __builtin_amdgcn_mfma_f32_16x16x32_bf16(Af[mt], Bf, acc[mt][nt], 0, 0, 0);
    }
  }
  if (xf) {
    float g = gate[0];
    #pragma unroll
    for (int mt = 0; mt < 4; ++mt) {
      int rowb = m0 + wm * 64 + mt * 16 + quad * 4;
      #pragma unroll
      for (int r = 0; r < 4; ++r) {
        #pragma unroll
        for (int nt = 0; nt < 4; ++nt) {
          float v = acc[mt][nt][r];
          float s = v, q = v * v;
          s += __shfl_xor(s, 1); q += __shfl_xor(q, 1);
          s += __shfl_xor(s, 2); q += __shfl_xor(q, 2);
          s += __shfl_xor(s, 4); q += __shfl_xor(q, 4);
          float m = s * 0.125f;
          float var = q * 0.125f - m * m;
          float norm = (v - m) * rsqrtf(var + 1e-5f);
          int col = n0 + wn * 64 + nt * 16 + lm;
          size_t idx = (size_t)(rowb + r) * 256 + col;
          xf[idx] += g * norm;
        }
      }
    }
  } else {
    #pragma unroll
    for (int nt = 0; nt < 4; ++nt) {
      int col = n0 + wn * 64 + nt * 16 + lm;
      #pragma unroll
      for (int mt = 0; mt < 4; ++mt) {
        int row = m0 + wm * 64 + mt * 16 + quad * 4;
        #pragma unroll
        for (int r = 0; r < 4; ++r)
          Cb[(size_t)(row + r) * ldc + col] = f2bf(acc[mt][nt][r]);
      }
    }
  }
}

// ---------------- fp32 GEMM (tiny out3 matmul) ----------------
__global__ __launch_bounds__(256) void gemm_k(const float* __restrict__ A, int lda,
    const float* __restrict__ Bm, int N, const float* __restrict__ bias,
    float* __restrict__ Cm, int ldc) {
  __shared__ __align__(16) float sA[16][64];
  __shared__ __align__(16) float sB[16][64];
  int n0 = blockIdx.x * 64, m0 = blockIdx.y * 64;
  int tid = threadIdx.x;
  int tx = tid & 15, ty = tid >> 4;
  int arow = m0 + (tid >> 2), acol = (tid & 3) * 4;
  int brow = tid >> 4, bcol = (tid & 15) * 4;
  float acc[4][4] = {};
  for (int k0 = 0; k0 < 256; k0 += 16) {
    __syncthreads();
    float4 av = *(const float4*)&A[(size_t)arow * lda + k0 + acol];
    sA[acol + 0][tid >> 2] = av.x;
    sA[acol + 1][tid >> 2] = av.y;
    sA[acol + 2][tid >> 2] = av.z;
    sA[acol + 3][tid >> 2] = av.w;
    *(float4*)&sB[brow][bcol] = *(const float4*)&Bm[(k0 + brow) * N + n0 + bcol];
    __syncthreads();
    #pragma unroll
    for (int kk = 0; kk < 16; ++kk) {
      float4 a = *(const float4*)&sA[kk][ty * 4];
      float4 b = *(const float4*)&sB[kk][tx * 4];
      float aa[4] = {a.x, a.y, a.z, a.w};
      float bb[4] = {b.x, b.y, b.z, b.w};
      #pragma unroll
      for (int i = 0; i < 4; ++i)
        #pragma unroll
        for (int j = 0; j < 4; ++j)
          acc[i][j] += aa[i] * bb[j];
    }
  }
  #pragma unroll
  for (int i = 0; i < 4; ++i)
    #pragma unroll
    for (int j = 0; j < 4; ++j) {
      int n = n0 + tx * 4 + j;
      float v = acc[i][j];
      if (bias) v += bias[n];
      Cm[(size_t)(m0 + ty * 4 + i) * ldc + n] = v;
    }
}

// ---------------- transposes ----------------
__global__ __launch_bounds__(256) void xf_to_xt_k(const float* __restrict__ XF, float* __restrict__ XT) {
  int rowid = blockIdx.x * 4 + (threadIdx.x >> 6);
  int lane = threadIdx.x & 63;
  int b = rowid >> 14, f = (rowid >> 8) & 63, t = rowid & 255;
  int src = ((b * TT + t) * FF + f) * CC + lane * 4;
  int dst = rowid * CC + lane * 4;
  *(float4*)&XT[dst] = *(const float4*)&XF[src];
}

// out[b][c][f][t] = XT[rg][t][c] + bf2f(O2b[rl][t][c])
__global__ __launch_bounds__(256) void final_out_k(const float* __restrict__ XT,
    const unsigned short* __restrict__ O2b, float* __restrict__ out, int rbase) {
  __shared__ float sT[32][33];
  int bx = blockIdx.x;
  int rl = bx >> 6;
  int t0 = ((bx >> 3) & 7) * 32;
  int c0 = (bx & 7) * 32;
  int rg = rbase + rl;
  int b = rg >> 6, f = rg & 63;
  int tc = threadIdx.x & 31, tr = threadIdx.x >> 5;
  #pragma unroll
  for (int i = 0; i < 4; ++i) {
    int t = t0 + tr + i * 8;
    sT[tr + i * 8][tc] = XT[(size_t)rg * 65536 + t * 256 + c0 + tc]
                       + bf2f(O2b[(size_t)rl * 65536 + t * 256 + c0 + tc]);
  }
  __syncthreads();
  #pragma unroll
  for (int i = 0; i < 4; ++i) {
    int c = c0 + tr + i * 8;
    out[((b * CC + c) * FF + f) * TT + t0 + tc] = sT[tc][tr + i * 8];
  }
}

// ---------------- attention: frequency axis (seq 64), bf16 in, y bf16 -> q cols ----------------
__global__ __launch_bounds__(256) void attn2_k(unsigned short* __restrict__ Q) {
  __shared__ float sq[64][33], sk[64][33], sv[64][33];
  __shared__ float sS[64][65];
  __shared__ float sInv[64];
  int bt = blockIdx.x >> 3, h = blockIdx.x & 7;
  int tid = threadIdx.x;
  const float scale = 0.17677669529663687f;
  {
    int fq = tid >> 2, d8 = (tid & 3) * 8;
    size_t base = ((size_t)(bt * 64 + fq)) * 768 + h * 32 + d8;
    unpack8(*(const uint4*)&Q[base], &sq[fq][d8]);
    unpack8(*(const uint4*)&Q[base + 256], &sk[fq][d8]);
    unpack8(*(const uint4*)&Q[base + 512], &sv[fq][d8]);
  }
  __syncthreads();
  {
    int L = tid >> 2, lg = tid & 3;
    float a[16] = {};
    for (int d = 0; d < 32; ++d) {
      float qv = sq[L][d];
      #pragma unroll
      for (int j = 0; j < 16; ++j) a[j] += qv * sk[lg * 16 + j][d];
    }
    #pragma unroll
    for (int j = 0; j < 16; ++j) sS[L][lg * 16 + j] = a[j] * scale;
  }
  __syncthreads();
  if (tid < 64) {
    float mx = -1e30f;
    for (int l = 0; l < 64; ++l) mx = fmaxf(mx, sS[tid][l]);
    float sum = 0.f;
    for (int l = 0; l < 64; ++l) { float e = expf(sS[tid][l] - mx); sS[tid][l] = e; sum += e; }
    sInv[tid] = 1.f / sum;
  }
  __syncthreads();
  {
    int L = tid >> 2, dg = tid & 3;
    float a[8] = {};
    for (int l = 0; l < 64; ++l) {
      float p = sS[L][l];
      #pragma unroll
      for (int j = 0; j < 8; ++j) a[j] += p * sv[l][dg * 8 + j];
    }
    float r = sInv[L];
    uint4 pk;
    pk.x = packbf2(a[0] * r, a[1] * r);
    pk.y = packbf2(a[2] * r, a[3] * r);
    pk.z = packbf2(a[4] * r, a[5] * r);
    pk.w = packbf2(a[6] * r, a[7] * r);
    *(uint4*)&Q[((size_t)(bt * 64 + L)) * 768 + h * 32 + dg * 8] = pk;
  }
}

// ---------------- attention: global time (pooled q, seq 256), bf16 in ----------------
__global__ __launch_bounds__(256) void attn3_k(const unsigned short* __restrict__ Q3,
                                               float* __restrict__ y3, int bf_base) {
  __shared__ float part[8][32];
  __shared__ float sqm[32];
  __shared__ float sp[256];
  __shared__ float sred[256];
  int bfl = blockIdx.x >> 3, h = blockIdx.x & 7;
  int tid = threadIdx.x;
  int tg = tid >> 5, d = tid & 31;
  const float scale = 0.17677669529663687f;
  int rowbase = bfl * 256;
  float s = 0.f;
  for (int t = tg * 32; t < tg * 32 + 32; ++t) s += bf2f(Q3[(size_t)(rowbase + t) * 768 + h * 32 + d]);
  part[tg][d] = s;
  __syncthreads();
  if (tid < 32) {
    float m = 0.f;
    for (int g = 0; g < 8; ++g) m += part[g][tid];
    sqm[tid] = m * (1.f / 256.f);
  }
  __syncthreads();
  {
    float dot = 0.f;
    const unsigned short* kp = &Q3[(size_t)(rowbase + tid) * 768 + 256 + h * 32];
    for (int dd = 0; dd < 32; ++dd) dot += sqm[dd] * bf2f(kp[dd]);
    sp[tid] = dot * scale;
    sred[tid] = sp[tid];
  }
  __syncthreads();
  for (int st = 128; st > 0; st >>= 1) { if (tid < st) sred[tid] = fmaxf(sred[tid], sred[tid + st]); __syncthreads(); }
  float mx = sred[0];
  __syncthreads();
  float e = expf(sp[tid] - mx);
  sred[tid] = e;
  __syncthreads();
  for (int st = 128; st > 0; st >>= 1) { if (tid < st) sred[tid] += sred[tid + st]; __syncthreads(); }
  float rinv = 1.f / sred[0];
  sp[tid] = e * rinv;
  __syncthreads();
  float acc = 0.f;
  for (int t = tg * 32; t < tg * 32 + 32; ++t)
    acc += sp[t] * bf2f(Q3[(size_t)(rowbase + t) * 768 + 512 + h * 32 + d]);
  part[tg][d] = acc;
  __syncthreads();
  if (tid < 32) {
    float o = 0.f;
    for (int g = 0; g < 8; ++g) o += part[g][tid];
    y3[(size_t)(bf_base + bfl) * 256 + h * 32 + tid] = o;
  }
}

// ---------------- LSA: local window 16 along T, bf16 in, o bf16 -> q cols ----------------
__global__ __launch_bounds__(256) void lsa_attn_k(unsigned short* __restrict__ Q4) {
  __shared__ __align__(16) float sX[16][772];
  __shared__ float sS[8][16][17];
  __shared__ float sInv[8][16];
  int bfl = blockIdx.x >> 4, w = blockIdx.x & 15;
  int tid = threadIdx.x;
  size_t rb = ((size_t)(bfl * 256 + w * 16)) * 768;
  for (int s = tid; s < 1536; s += 256) {
    int t = s / 96, c8 = (s - t * 96) * 8;
    unpack8(*(const uint4*)&Q4[rb + t * 768 + c8], &sX[t][c8]);
  }
  __syncthreads();
  const float scale = 0.17677669529663687f;
  #pragma unroll
  for (int rep = 0; rep < 8; ++rep) {
    int idx = tid + rep * 256;
    int h = idx >> 8, q = (idx >> 4) & 15, k = idx & 15;
    float dot = 0.f;
    const float* qp = &sX[q][h * 32];
    const float* kp = &sX[k][256 + h * 32];
    for (int d = 0; d < 32; ++d) dot += qp[d] * kp[d];
    sS[h][q][k] = dot * scale;
  }
  __syncthreads();
  if (tid < 128) {
    int h = tid >> 4, q = tid & 15;
    float mx = -1e30f;
    for (int k = 0; k < 16; ++k) mx = fmaxf(mx, sS[h][q][k]);
    float sum = 0.f;
    for (int k = 0; k < 16; ++k) { float e = expf(sS[h][q][k] - mx); sS[h][q][k] = e; sum += e; }
    sInv[h][q] = 1.f / sum;
  }
  __syncthreads();
  #pragma unroll
  for (int rep = 0; rep < 8; ++rep) {
    int idx = tid + rep * 256;
    int t = idx >> 7, c2 = (idx & 127) * 2;
    int h = c2 >> 5;
    float a0 = 0.f, a1 = 0.f;
    for (int k = 0; k < 16; ++k) {
      float p = sS[h][t][k];
      a0 += p * sX[k][512 + c2];
      a1 += p * sX[k][512 + c2 + 1];
    }
    float riv = sInv[h][t];
    *(unsigned*)&Q4[rb + t * 768 + c2] = packbf2(a0 * riv, a1 * riv);
  }
}

// ---------------- small GN / broadcast ----------------
__global__ void gn_rows_k(const float* __restrict__ src, float* __restrict__ dst, int total) {
  int s = blockIdx.x * 256 + threadIdx.x;
  if (s >= total) return;
  int base = s * 8;
  float4 a = *(const float4*)&src[base];
  float4 b = *(const float4*)&src[base + 4];
  float m = (a.x + a.y + a.z + a.w + b.x + b.y + b.z + b.w) * 0.125f;
  float q = (a.x * a.x + a.y * a.y + a.z * a.z + a.w * a.w +
             b.x * b.x + b.y * b.y + b.z * b.z + b.w * b.w) * 0.125f - m * m;
  float r = rsqrtf(q + 1e-5f);
  a.x = (a.x - m) * r; a.y = (a.y - m) * r; a.z = (a.z - m) * r; a.w = (a.w - m) * r;
  b.x = (b.x - m) * r; b.y = (b.y - m) * r; b.z = (b.z - m) * r; b.w = (b.w - m) * r;
  *(float4*)&dst[base] = a;
  *(float4*)&dst[base + 4] = b;
}

__global__ __launch_bounds__(256) void bcast_add_k(float* __restrict__ XT, const float* __restrict__ y3n,
                                                   const float* __restrict__ gate) {
  int i4 = blockIdx.x * 256 + threadIdx.x;
  int flat = i4 * 4;
  int r = flat >> 16, c = flat & 255;
  float g = gate[0];
  float4 v = ((float4*)XT)[i4];
  float4 a = *(const float4*)&y3n[r * 256 + c];
  v.x += g * a.x; v.y += g * a.y; v.z += g * a.z; v.w += g * a.w;
  ((float4*)XT)[i4] = v;
}

__global__ __launch_bounds__(256) void gn_stats_xt_k(const float* __restrict__ X, float* __restrict__ stats) {
  __shared__ float sbuf[8];
  int bx = blockIdx.x;
  int b = bx >> 11, g = (bx >> 6) & 31, f = bx & 63;
  size_t base = (size_t)(b * 64 + f) * 65536 + g * 8;
  float s = 0.f, ss = 0.f;
  for (int i = threadIdx.x; i < 2048; i += 256) {
    int t = i >> 3, c = i & 7;
    float v = X[base + t * 256 + c];
    s += v; ss += v * v;
  }
  blockReduce2(s, ss, sbuf);
  if (threadIdx.x == 0) { atomicAdd(&stats[b * 32 + g], s); atomicAdd(&stats[128 + b * 32 + g], ss); }
}

// ---------------- launch ----------------
extern "C" void kernel_launch(void* const* d_in, const int* in_sizes, int n_in,
                              void* d_out, int out_size, void* d_ws, size_t ws_size,
                              hipStream_t stream) {
  (void)in_sizes; (void)n_in; (void)out_size;
  const float* x        = (const float*)d_in[0];
  const float* temb     = (const float*)d_in[1];
  const float* conv1_w  = (const float*)d_in[2];
  const float* conv1_b  = (const float*)d_in[3];
  const float* conv2_w  = (const float*)d_in[4];
  const float* g_diff   = (const float*)d_in[5];
  const float* g_res    = (const float*)d_in[6];
  const float* g2       = (const float*)d_in[7];
  const float* g3       = (const float*)d_in[8];
  const float* qkv2_w   = (const float*)d_in[9];
  const float* qkv2_b   = (const float*)d_in[10];
  const float* out2_w   = (const float*)d_in[11];
  const float* qkv3_w   = (const float*)d_in[12];
  const float* qkv3_b   = (const float*)d_in[13];
  const float* out3_w   = (const float*)d_in[14];
  const float* lsa_qkv_w = (const float*)d_in[15];
  const float* lsa_out_w = (const float*)d_in[16];
  float* out = (float*)d_out;
  float* ws = (float*)d_ws;

  // adaptive chunking: pick largest chunk size that fits ws
  int NCHv = 4;
  {
    auto need = [](int nch) -> size_t {
      size_t rows = 65536 / nch;
      size_t uslots = rows * 512;
      if (uslots < 8388608) uslots = 8388608;
      return 4ull * ((size_t)NN + uslots + 950272 + 196864 + 256);
    };
    if (ws_size >= need(1)) NCHv = 1;
    else if (ws_size >= need(2)) NCHv = 2;
  }
  const size_t rows = 65536 / NCHv;

  float* W = ws;                                  // NN fp32 trunk
  float* U = ws + (size_t)NN;                     // union region
  unsigned short* XC  = (unsigned short*)U;       // NN bf16 (conv staging)
  unsigned short* QB  = (unsigned short*)U;       // rows*768 bf16 (qkv)
  unsigned short* O2B = (unsigned short*)(U + rows * 384);  // rows*256 bf16
  size_t uslots = rows * 512; if (uslots < 8388608) uslots = 8388608;
  float* WREG = U + uslots;
  unsigned short* WB1   = (unsigned short*)WREG;
  unsigned short* WB2   = WB1 + 589824;
  unsigned short* QKV2T = WB2 + 589824;
  unsigned short* OUT2T = QKV2T + 196608;
  unsigned short* QKV3T = OUT2T + 65536;
  unsigned short* LSAQT = QKV3T + 196608;
  unsigned short* LSAOT = LSAQT + 196608;
  float* Y3    = WREG + 950272;
  float* Y3O   = Y3 + 65536;
  float* Y3N   = Y3O + 65536;
  float* STATS = Y3N + 65536;
  float* D = out;                                 // d_out as scratch until final stage

  dim3 b256(256);
  convw_bf_k<<<2304, b256, 0, stream>>>(conv1_w, WB1);
  convw_bf_k<<<2304, b256, 0, stream>>>(conv2_w, WB2);
  matT_bf_k<<<768, b256, 0, stream>>>(qkv2_w, QKV2T, 768, 196608);
  matT_bf_k<<<256, b256, 0, stream>>>(out2_w, OUT2T, 256, 65536);
  matT_bf_k<<<768, b256, 0, stream>>>(qkv3_w, QKV3T, 768, 196608);
  matT_bf_k<<<768, b256, 0, stream>>>(lsa_qkv_w, LSAQT, 768, 196608);
  matT_bf_k<<<256, b256, 0, stream>>>(lsa_out_w, LSAOT, 256, 65536);

  // ---- residual block ----
  zero_stats_k<<<1, b256, 0, stream>>>(STATS);
  gn_stats_contig<<<1024, b256, 0, stream>>>(x, STATS);
  gn_apply_tr_k<<<16384, b256, 0, stream>>>(x, STATS, XC, 1e-6f);
  conv3x3_mfma_k<<<dim3(64, 8), b256, 0, stream>>>(XC, WB1, conv1_b, temb, g_diff, W, 1);
  zero_stats_k<<<1, b256, 0, stream>>>(STATS);
  gn_stats_contig<<<1024, b256, 0, stream>>>(W, STATS);
  gn_apply_tr_k<<<16384, b256, 0, stream>>>(W, STATS, XC, 1e-6f);
  conv3x3_mfma_k<<<dim3(64, 8), b256, 0, stream>>>(XC, WB2, nullptr, nullptr, nullptr, W, 0);
  zero_stats_k<<<1, b256, 0, stream>>>(STATS);
  gn_stats_contig<<<1024, b256, 0, stream>>>(W, STATS);
  gn_tr_resid_k<<<16384, b256, 0, stream>>>(W, x, STATS, g_res, D, 1e-6f);  // D = xf

  // ---- layer2: freq attention ----
  for (int c = 0; c < NCHv; ++c) {
    float* XFr = D + (size_t)c * rows * 256;
    gemm_af32_k<<<dim3(6, rows / 128), b256, 0, stream>>>(XFr, 256, QKV2T, qkv2_b, QB, 768, nullptr, 0, 0.f);
    attn2_k<<<(rows / 64) * 8, b256, 0, stream>>>(QB);
    gemm_abf16_k<<<dim3(2, rows / 128), b256, 0, stream>>>(QB, 768, OUT2T, XFr, nullptr, 256, g2);
  }

  // ---- layer3: global time attention ----
  xf_to_xt_k<<<16384, b256, 0, stream>>>(D, W);   // W = xt
  for (int c = 0; c < NCHv; ++c) {
    const float* XTr = W + (size_t)c * rows * 256;
    gemm_af32_k<<<dim3(6, rows / 128), b256, 0, stream>>>(XTr, 256, QKV3T, qkv3_b, QB, 768, nullptr, 0, 0.f);
    attn3_k<<<(rows / 256) * 8, b256, 0, stream>>>(QB, Y3, c * (int)(rows / 256));
  }
  gemm_k<<<dim3(4, 4), b256, 0, stream>>>(Y3, 256, out3_w, 256, nullptr, Y3O, 256);
  gn_rows_k<<<32, b256, 0, stream>>>(Y3O, Y3N, 8192);
  bcast_add_k<<<16384, b256, 0, stream>>>(W, Y3N, g3);

  // ---- layer4: LSA ----
  zero_stats_k<<<1, b256, 0, stream>>>(STATS);
  gn_stats_xt_k<<<8192, b256, 0, stream>>>(W, STATS);
  for (int c = 0; c < NCHv; ++c) {
    const float* XTr = W + (size_t)c * rows * 256;
    gemm_af32_k<<<dim3(6, rows / 128), b256, 0, stream>>>(XTr, 256, LSAQT, nullptr, QB, 768,
                                                          STATS, (int)(c * rows), 1e-5f);
    lsa_attn_k<<<(rows / 256) * 16, b256, 0, stream>>>(QB);
    gemm_abf16_k<<<dim3(2, rows / 128), b256, 0, stream>>>(QB, 768, LSAOT, nullptr, O2B, 256, nullptr);
    final_out_k<<<(rows / 256) * 64, b256, 0, stream>>>(W, O2B, out, c * (int)(rows / 256));
  }
}

// Round 5
// 1115.959 us; speedup vs baseline: 4.8062x; 1.1359x over previous
//
#include <hip/hip_runtime.h>

#define NN 16777216   // 4*256*64*256
#define CC 256
#define FF 64
#define TT 256

typedef short v8s __attribute__((ext_vector_type(8)));
typedef float v4f __attribute__((ext_vector_type(4)));

__device__ __forceinline__ unsigned short f2bf(float f) {
  unsigned u = __float_as_uint(f);
  u += 0x7fff + ((u >> 16) & 1);
  return (unsigned short)(u >> 16);
}
__device__ __forceinline__ float bf2f(unsigned short h) {
  return __uint_as_float(((unsigned)h) << 16);
}
__device__ __forceinline__ unsigned packbf2(float a, float b) {
  return (unsigned)f2bf(a) | ((unsigned)f2bf(b) << 16);
}
__device__ __forceinline__ void unpack8(uint4 u, float* d) {
  d[0] = __uint_as_float(u.x << 16); d[1] = __uint_as_float(u.x & 0xffff0000u);
  d[2] = __uint_as_float(u.y << 16); d[3] = __uint_as_float(u.y & 0xffff0000u);
  d[4] = __uint_as_float(u.z << 16); d[5] = __uint_as_float(u.z & 0xffff0000u);
  d[6] = __uint_as_float(u.w << 16); d[7] = __uint_as_float(u.w & 0xffff0000u);
}

// ---------------- helpers ----------------
__device__ __forceinline__ void blockReduce2(float& a, float& b, float* sbuf) {
  #pragma unroll
  for (int off = 32; off > 0; off >>= 1) {
    a += __shfl_down(a, off, 64);
    b += __shfl_down(b, off, 64);
  }
  int w = threadIdx.x >> 6;
  if ((threadIdx.x & 63) == 0) { sbuf[w] = a; sbuf[4 + w] = b; }
  __syncthreads();
  if (threadIdx.x == 0) {
    a = sbuf[0] + sbuf[1] + sbuf[2] + sbuf[3];
    b = sbuf[4] + sbuf[5] + sbuf[6] + sbuf[7];
  }
}

__global__ void zero_stats_k(float* p) { p[threadIdx.x] = 0.f; }

// ---------------- weight prep ----------------
__global__ void convw_bf_k(const float* __restrict__ w, unsigned short* __restrict__ wb) {
  int s = blockIdx.x * 256 + threadIdx.x;
  if (s < 589824) {
    int co = s / 2304, r = s % 2304;
    int ci = r / 9, tap = r % 9;
    wb[(tap * 256 + co) * 256 + ci] = f2bf(w[s]);
  }
}

__global__ void matT_bf_k(const float* __restrict__ w, unsigned short* __restrict__ bt, int N, int total) {
  int s = blockIdx.x * 256 + threadIdx.x;
  if (s < total) {
    int k = s / N, n = s % N;
    bt[n * 256 + k] = f2bf(w[s]);
  }
}

// ---------------- GroupNorm stats (NCHW contiguous: 131072/group) ----------------
__global__ __launch_bounds__(256) void gn_stats_contig(const float* __restrict__ src, float* __restrict__ stats) {
  __shared__ float sbuf[8];
  int grp = blockIdx.x >> 3, chunk = blockIdx.x & 7;
  const float4* p = (const float4*)src + grp * 32768 + chunk * 4096;
  float s = 0.f, ss = 0.f;
  for (int i = threadIdx.x; i < 4096; i += 256) {
    float4 v = p[i];
    s += v.x + v.y + v.z + v.w;
    ss += v.x * v.x + v.y * v.y + v.z * v.z + v.w * v.w;
  }
  blockReduce2(s, ss, sbuf);
  if (threadIdx.x == 0) { atomicAdd(&stats[grp], s); atomicAdd(&stats[128 + grp], ss); }
}

// GN apply + transpose to bf16 [b][f][t][ci]
__global__ __launch_bounds__(256) void gn_apply_tr_k(const float* __restrict__ src,
    const float* __restrict__ stats, unsigned short* __restrict__ XC, float eps) {
  __shared__ float sT[32][33];
  int bx = blockIdx.x;
  int r = bx >> 6;
  int c0 = ((bx >> 3) & 7) * 32;
  int t0 = (bx & 7) * 32;
  int b = r >> 6, f = r & 63;
  int tl = threadIdx.x & 31, tr = threadIdx.x >> 5;
  #pragma unroll
  for (int i = 0; i < 4; ++i) {
    int c = c0 + tr + i * 8;
    int grp = b * 32 + (c >> 3);
    float mean = stats[grp] * (1.f / 131072.f);
    float var = stats[128 + grp] * (1.f / 131072.f) - mean * mean;
    float rv = rsqrtf(var + eps);
    float v = src[((b * 256 + c) * 64 + f) * 256 + t0 + tl];
    sT[tr + i * 8][tl] = (v - mean) * rv;
  }
  __syncthreads();
  #pragma unroll
  for (int i = 0; i < 4; ++i) {
    int t = t0 + tr + i * 8;
    XC[(((size_t)(b * 64 + f)) * 256 + t) * 256 + c0 + tl] = f2bf(sT[tl][tr + i * 8]);
  }
}

// GN apply + gated residual + transpose to XF fp32 [(b*256+t)*64+f][c]
__global__ __launch_bounds__(256) void gn_tr_resid_k(const float* __restrict__ h,
    const float* __restrict__ x, const float* __restrict__ stats,
    const float* __restrict__ gate, float* __restrict__ XF, float eps) {
  __shared__ float sT[32][33];
  int bx = blockIdx.x;
  int r = bx >> 6;
  int c0 = ((bx >> 3) & 7) * 32;
  int t0 = (bx & 7) * 32;
  int b = r >> 6, f = r & 63;
  int tl = threadIdx.x & 31, tr = threadIdx.x >> 5;
  float g = gate[0];
  #pragma unroll
  for (int i = 0; i < 4; ++i) {
    int c = c0 + tr + i * 8;
    int grp = b * 32 + (c >> 3);
    float mean = stats[grp] * (1.f / 131072.f);
    float var = stats[128 + grp] * (1.f / 131072.f) - mean * mean;
    float rv = rsqrtf(var + eps);
    int idx = ((b * 256 + c) * 64 + f) * 256 + t0 + tl;
    sT[tr + i * 8][tl] = x[idx] + g * (h[idx] - mean) * rv;
  }
  __syncthreads();
  #pragma unroll
  for (int i = 0; i < 4; ++i) {
    int t = t0 + tr + i * 8;
    XF[(((size_t)(b * 256 + t)) * 64 + f) * 256 + c0 + tl] = sT[tl][tr + i * 8];
  }
}

// ---------------- conv 3x3 via MFMA (implicit GEMM, bf16 pre-transposed input) ----------------
__global__ __launch_bounds__(256, 2) void conv3x3_mfma_k(const unsigned short* __restrict__ XC,
    const unsigned short* __restrict__ wb, const float* __restrict__ bias,
    const float* __restrict__ temb, const float* __restrict__ gd,
    float* __restrict__ out, int mode) {
  __shared__ __align__(16) unsigned short sIn[3][258][40];
  __shared__ __align__(16) unsigned short sW[128][40];
  int f  = blockIdx.x;
  int b  = blockIdx.y >> 1;
  int co0 = (blockIdx.y & 1) * 128;
  int tid = threadIdx.x;
  int wave = tid >> 6, lane = tid & 63;
  int lm = lane & 15, quad = lane >> 4;
  int w64 = wave * 64;
  v4f acc[4][8];
  #pragma unroll
  for (int i = 0; i < 4; ++i)
    #pragma unroll
    for (int j = 0; j < 8; ++j) acc[i][j] = (v4f)(0.f);

  for (int ci0 = 0; ci0 < 256; ci0 += 32) {
    __syncthreads();
    for (int s = tid; s < 3096; s += 256) {
      int df = s / 1032, r = s - df * 1032;
      int tl = r >> 2, part = r & 3;
      int fi = f + df - 1, tg = tl - 1;
      uint4 val = make_uint4(0, 0, 0, 0);
      if (fi >= 0 && fi < 64 && tg >= 0 && tg < 256)
        val = *(const uint4*)&XC[(((size_t)(b * 64 + fi)) * 256 + tg) * 256 + ci0 + part * 8];
      *(uint4*)&sIn[df][tl][part * 8] = val;
    }
    for (int tap = 0; tap < 9; ++tap) {
      __syncthreads();
      {
        int co = tid >> 2, part = tid & 3;
        *(uint4*)&sW[co][part * 8] =
            *(const uint4*)&wb[((size_t)(tap * 256) + co0 + co) * 256 + ci0 + part * 8];
        int s1 = tid + 256;
        co = s1 >> 2; part = s1 & 3;
        *(uint4*)&sW[co][part * 8] =
            *(const uint4*)&wb[((size_t)(tap * 256) + co0 + co) * 256 + ci0 + part * 8];
      }
      __syncthreads();
      int df = tap / 3, dt = tap - df * 3;
      v8s A[4];
      #pragma unroll
      for (int mt = 0; mt < 4; ++mt)
        A[mt] = *(const v8s*)&sIn[df][w64 + mt * 16 + lm + dt][quad * 8];
      #pragma unroll
      for (int nt = 0; nt < 8; ++nt) {
        v8s B = *(const v8s*)&sW[nt * 16 + lm][quad * 8];
        #pragma unroll
        for (int mt = 0; mt < 4; ++mt)
          acc[mt][nt] = __builtin_amdgcn_mfma_f32_16x16x32_bf16(A[mt], B, acc[mt][nt], 0, 0, 0);
      }
    }
  }
  float gdv = mode ? gd[0] : 0.f;
  #pragma unroll
  for (int nt = 0; nt < 8; ++nt) {
    int co = co0 + nt * 16 + lm;
    float bb = 0.f;
    if (mode) bb = bias[co] + gdv * temb[b * 256 + co];
    #pragma unroll
    for (int mt = 0; mt < 4; ++mt) {
      int t = w64 + mt * 16 + quad * 4;
      float v0 = acc[mt][nt][0] + bb, v1 = acc[mt][nt][1] + bb;
      float v2 = acc[mt][nt][2] + bb, v3 = acc[mt][nt][3] + bb;
      if (mode) {
        v0 = v0 / (1.f + expf(-v0)); v1 = v1 / (1.f + expf(-v1));
        v2 = v2 / (1.f + expf(-v2)); v3 = v3 / (1.f + expf(-v3));
      }
      float4 o; o.x = v0; o.y = v1; o.z = v2; o.w = v3;
      *(float4*)&out[(((size_t)b * 256 + co) * 64 + f) * 256 + t] = o;
    }
  }
}

// ---------------- MFMA GEMM: Cb bf16 [M,N] = gn?(A fp32 [M,256]) @ B (+bias) ----------------
__global__ __launch_bounds__(256) void gemm_af32_k(const float* __restrict__ A, int lda,
    const unsigned short* __restrict__ BT, const float* __restrict__ bias,
    unsigned short* __restrict__ Cb, int ldc,
    const float* __restrict__ gstats, int growbase, float eps) {
  __shared__ __align__(16) unsigned short sA[128][40];
  __shared__ __align__(16) unsigned short sB[128][40];
  int n0 = blockIdx.x * 128, m0 = blockIdx.y * 128;
  int tid = threadIdx.x;
  int wave = tid >> 6, lane = tid & 63;
  int wm = wave >> 1, wn = wave & 1;
  int lm = lane & 15, quad = lane >> 4;
  v4f acc[4][4];
  #pragma unroll
  for (int i = 0; i < 4; ++i)
    #pragma unroll
    for (int j = 0; j < 4; ++j) acc[i][j] = (v4f)(0.f);

  for (int k0 = 0; k0 < 256; k0 += 32) {
    __syncthreads();
    #pragma unroll
    for (int i = 0; i < 4; ++i) {
      int s = tid + i * 256;
      int row = s >> 3, k4 = s & 7;
      float4 av = *(const float4*)&A[(size_t)(m0 + row) * lda + k0 + k4 * 4];
      if (gstats) {
        int grp = ((growbase + m0 + row) >> 14) * 32 + ((k0 + k4 * 4) >> 3);
        float mean = gstats[grp] * (1.f / 131072.f);
        float var = gstats[128 + grp] * (1.f / 131072.f) - mean * mean;
        float rr = rsqrtf(var + eps);
        av.x = (av.x - mean) * rr; av.y = (av.y - mean) * rr;
        av.z = (av.z - mean) * rr; av.w = (av.w - mean) * rr;
      }
      *(uint2*)&sA[row][k4 * 4] = make_uint2(packbf2(av.x, av.y), packbf2(av.z, av.w));
    }
    #pragma unroll
    for (int i = 0; i < 2; ++i) {
      int s = tid + i * 256;
      int n = s >> 2, part = s & 3;
      *(uint4*)&sB[n][part * 8] = *(const uint4*)&BT[(size_t)(n0 + n) * 256 + k0 + part * 8];
    }
    __syncthreads();
    v8s Af[4];
    #pragma unroll
    for (int mt = 0; mt < 4; ++mt)
      Af[mt] = *(const v8s*)&sA[wm * 64 + mt * 16 + lm][quad * 8];
    #pragma unroll
    for (int nt = 0; nt < 4; ++nt) {
      v8s Bf = *(const v8s*)&sB[wn * 64 + nt * 16 + lm][quad * 8];
      #pragma unroll
      for (int mt = 0; mt < 4; ++mt)
        acc[mt][nt] = __builtin_amdgcn_mfma_f32_16x16x32_bf16(Af[mt], Bf, acc[mt][nt], 0, 0, 0);
    }
  }
  #pragma unroll
  for (int nt = 0; nt < 4; ++nt) {
    int col = n0 + wn * 64 + nt * 16 + lm;
    float bb = bias ? bias[col] : 0.f;
    #pragma unroll
    for (int mt = 0; mt < 4; ++mt) {
      int row = m0 + wm * 64 + mt * 16 + quad * 4;
      #pragma unroll
      for (int r = 0; r < 4; ++r)
        Cb[(size_t)(row + r) * ldc + col] = f2bf(acc[mt][nt][r] + bb);
    }
  }
}

// ---------------- MFMA GEMM, A bf16: either bf16 C out, or fused rowGN+gate+add into xf ----------------
__global__ __launch_bounds__(256) void gemm_abf16_k(const unsigned short* __restrict__ A, int lda,
    const unsigned short* __restrict__ BT, float* __restrict__ xf,
    unsigned short* __restrict__ Cb, int ldc, const float* __restrict__ gate) {
  __shared__ __align__(16) unsigned short sA[128][40];
  __shared__ __align__(16) unsigned short sB[128][40];
  int n0 = blockIdx.x * 128, m0 = blockIdx.y * 128;
  int tid = threadIdx.x;
  int wave = tid >> 6, lane = tid & 63;
  int wm = wave >> 1, wn = wave & 1;
  int lm = lane & 15, quad = lane >> 4;
  v4f acc[4][4];
  #pragma unroll
  for (int i = 0; i < 4; ++i)
    #pragma unroll
    for (int j = 0; j < 4; ++j) acc[i][j] = (v4f)(0.f);

  for (int k0 = 0; k0 < 256; k0 += 32) {
    __syncthreads();
    #pragma unroll
    for (int i = 0; i < 2; ++i) {
      int s = tid + i * 256;
      int row = s >> 2, part = s & 3;
      *(uint4*)&sA[row][part * 8] = *(const uint4*)&A[(size_t)(m0 + row) * lda + k0 + part * 8];
      *(uint4*)&sB[row][part * 8] = *(const uint4*)&BT[(size_t)(n0 + row) * 256 + k0 + part * 8];
    }
    __syncthreads();
    v8s Af[4];
    #pragma unroll
    for (int mt = 0; mt < 4; ++mt)
      Af[mt] = *(const v8s*)&sA[wm * 64 + mt * 16 + lm][quad * 8];
    #pragma unroll
    for (int nt = 0; nt < 4; ++nt) {
      v8s Bf = *(const v8s*)&sB[wn * 64 + nt * 16 + lm][quad * 8];
      #pragma unroll
      for (int mt = 0; mt < 4; ++mt)
        acc[mt][nt] = __builtin_amdgcn_mfma_f32_16x16x32_bf16(Af[mt], Bf, acc[mt][nt], 0, 0, 0);
    }
  }
  if (xf) {
    float g = gate[0];
    #pragma unroll
    for (int mt = 0; mt < 4; ++mt) {
      int rowb = m0 + wm * 64 + mt * 16 + quad * 4;
      #pragma unroll
      for (int r = 0; r < 4; ++r) {
        #pragma unroll
        for (int nt = 0; nt < 4; ++nt) {
          float v = acc[mt][nt][r];
          float s = v, q = v * v;
          s += __shfl_xor(s, 1); q += __shfl_xor(q, 1);
          s += __shfl_xor(s, 2); q += __shfl_xor(q, 2);
          s += __shfl_xor(s, 4); q += __shfl_xor(q, 4);
          float m = s * 0.125f;
          float var = q * 0.125f - m * m;
          float norm = (v - m) * rsqrtf(var + 1e-5f);
          int col = n0 + wn * 64 + nt * 16 + lm;
          size_t idx = (size_t)(rowb + r) * 256 + col;
          xf[idx] += g * norm;
        }
      }
    }
  } else {
    #pragma unroll
    for (int nt = 0; nt < 4; ++nt) {
      int col = n0 + wn * 64 + nt * 16 + lm;
      #pragma unroll
      for (int mt = 0; mt < 4; ++mt) {
        int row = m0 + wm * 64 + mt * 16 + quad * 4;
        #pragma unroll
        for (int r = 0; r < 4; ++r)
          Cb[(size_t)(row + r) * ldc + col] = f2bf(acc[mt][nt][r]);
      }
    }
  }
}

// ---------------- fp32 GEMM (tiny out3 matmul) ----------------
__global__ __launch_bounds__(256) void gemm_k(const float* __restrict__ A, int lda,
    const float* __restrict__ Bm, int N, const float* __restrict__ bias,
    float* __restrict__ Cm, int ldc) {
  __shared__ __align__(16) float sA[16][64];
  __shared__ __align__(16) float sB[16][64];
  int n0 = blockIdx.x * 64, m0 = blockIdx.y * 64;
  int tid = threadIdx.x;
  int tx = tid & 15, ty = tid >> 4;
  int arow = m0 + (tid >> 2), acol = (tid & 3) * 4;
  int brow = tid >> 4, bcol = (tid & 15) * 4;
  float acc[4][4] = {};
  for (int k0 = 0; k0 < 256; k0 += 16) {
    __syncthreads();
    float4 av = *(const float4*)&A[(size_t)arow * lda + k0 + acol];
    sA[acol + 0][tid >> 2] = av.x;
    sA[acol + 1][tid >> 2] = av.y;
    sA[acol + 2][tid >> 2] = av.z;
    sA[acol + 3][tid >> 2] = av.w;
    *(float4*)&sB[brow][bcol] = *(const float4*)&Bm[(k0 + brow) * N + n0 + bcol];
    __syncthreads();
    #pragma unroll
    for (int kk = 0; kk < 16; ++kk) {
      float4 a = *(const float4*)&sA[kk][ty * 4];
      float4 b = *(const float4*)&sB[kk][tx * 4];
      float aa[4] = {a.x, a.y, a.z, a.w};
      float bb[4] = {b.x, b.y, b.z, b.w};
      #pragma unroll
      for (int i = 0; i < 4; ++i)
        #pragma unroll
        for (int j = 0; j < 4; ++j)
          acc[i][j] += aa[i] * bb[j];
    }
  }
  #pragma unroll
  for (int i = 0; i < 4; ++i)
    #pragma unroll
    for (int j = 0; j < 4; ++j) {
      int n = n0 + tx * 4 + j;
      float v = acc[i][j];
      if (bias) v += bias[n];
      Cm[(size_t)(m0 + ty * 4 + i) * ldc + n] = v;
    }
}

// ---------------- transposes ----------------
__global__ __launch_bounds__(256) void xf_to_xt_k(const float* __restrict__ XF, float* __restrict__ XT) {
  int rowid = blockIdx.x * 4 + (threadIdx.x >> 6);
  int lane = threadIdx.x & 63;
  int b = rowid >> 14, f = (rowid >> 8) & 63, t = rowid & 255;
  int src = ((b * TT + t) * FF + f) * CC + lane * 4;
  int dst = rowid * CC + lane * 4;
  *(float4*)&XT[dst] = *(const float4*)&XF[src];
}

// out[b][c][f][t] = XT[rg][t][c] + bf2f(O2b[rl][t][c])
__global__ __launch_bounds__(256) void final_out_k(const float* __restrict__ XT,
    const unsigned short* __restrict__ O2b, float* __restrict__ out, int rbase) {
  __shared__ float sT[32][33];
  int bx = blockIdx.x;
  int rl = bx >> 6;
  int t0 = ((bx >> 3) & 7) * 32;
  int c0 = (bx & 7) * 32;
  int rg = rbase + rl;
  int b = rg >> 6, f = rg & 63;
  int tc = threadIdx.x & 31, tr = threadIdx.x >> 5;
  #pragma unroll
  for (int i = 0; i < 4; ++i) {
    int t = t0 + tr + i * 8;
    sT[tr + i * 8][tc] = XT[(size_t)rg * 65536 + t * 256 + c0 + tc]
                       + bf2f(O2b[(size_t)rl * 65536 + t * 256 + c0 + tc]);
  }
  __syncthreads();
  #pragma unroll
  for (int i = 0; i < 4; ++i) {
    int c = c0 + tr + i * 8;
    out[((b * CC + c) * FF + f) * TT + t0 + tc] = sT[tc][tr + i * 8];
  }
}

// ---------------- attention: frequency axis (seq 64) via MFMA, in-place y -> q cols ----------------
// One block per bt group (64 rows); 4 waves x 2 heads each; no __syncthreads.
__global__ __launch_bounds__(256) void attn2_mfma_k(unsigned short* __restrict__ Q) {
  __shared__ __align__(16) unsigned short sP[4][64][72];
  __shared__ __align__(16) unsigned short sVt[4][32][72];
  int bt = blockIdx.x;
  int tid = threadIdx.x;
  int wave = tid >> 6, lane = tid & 63;
  int lm = lane & 15, quad = lane >> 4;
  const float scale = 0.17677669529663687f;
  size_t rowbase = (size_t)bt * 64;
  unsigned short (*P)[72] = sP[wave];
  unsigned short (*Vt)[72] = sVt[wave];
  #pragma unroll
  for (int hh = 0; hh < 2; ++hh) {
    int h = wave * 2 + hh;
    int hoff = h * 32;
    // --- QK^T: fragments straight from global ---
    v8s Af[4], Bf[4];
    #pragma unroll
    for (int mt = 0; mt < 4; ++mt)
      Af[mt] = *(const v8s*)&Q[(rowbase + mt * 16 + lm) * 768 + hoff + quad * 8];
    #pragma unroll
    for (int nt = 0; nt < 4; ++nt)
      Bf[nt] = *(const v8s*)&Q[(rowbase + nt * 16 + lm) * 768 + 256 + hoff + quad * 8];
    v4f S[4][4];
    #pragma unroll
    for (int mt = 0; mt < 4; ++mt)
      #pragma unroll
      for (int nt = 0; nt < 4; ++nt)
        S[mt][nt] = __builtin_amdgcn_mfma_f32_16x16x32_bf16(Af[mt], Bf[nt], (v4f)(0.f), 0, 0, 0);
    // --- stage V^T (d x seq) into LDS ---
    #pragma unroll
    for (int part = 0; part < 4; ++part) {
      uint4 u = *(const uint4*)&Q[(rowbase + lane) * 768 + 512 + hoff + part * 8];
      unsigned short* up = (unsigned short*)&u;
      #pragma unroll
      for (int j = 0; j < 8; ++j) Vt[part * 8 + j][lane] = up[j];
    }
    // --- softmax in registers (rows live in quads; reduce over lm group) ---
    float inv[4][4];
    #pragma unroll
    for (int mt = 0; mt < 4; ++mt) {
      #pragma unroll
      for (int r = 0; r < 4; ++r) {
        float v0 = S[mt][0][r] * scale, v1 = S[mt][1][r] * scale;
        float v2 = S[mt][2][r] * scale, v3 = S[mt][3][r] * scale;
        float mx = fmaxf(fmaxf(v0, v1), fmaxf(v2, v3));
        mx = fmaxf(mx, __shfl_xor(mx, 1));
        mx = fmaxf(mx, __shfl_xor(mx, 2));
        mx = fmaxf(mx, __shfl_xor(mx, 4));
        mx = fmaxf(mx, __shfl_xor(mx, 8));
        float e0 = __expf(v0 - mx), e1 = __expf(v1 - mx);
        float e2 = __expf(v2 - mx), e3 = __expf(v3 - mx);
        float sm = e0 + e1 + e2 + e3;
        sm += __shfl_xor(sm, 1);
        sm += __shfl_xor(sm, 2);
        sm += __shfl_xor(sm, 4);
        sm += __shfl_xor(sm, 8);
        inv[mt][r] = 1.f / sm;
        int row = mt * 16 + quad * 4 + r;
        P[row][lm]      = f2bf(e0);
        P[row][16 + lm] = f2bf(e1);
        P[row][32 + lm] = f2bf(e2);
        P[row][48 + lm] = f2bf(e3);
      }
    }
    // --- PV ---
    v8s Ap[4][2], Bv[2][2];
    #pragma unroll
    for (int mt = 0; mt < 4; ++mt)
      #pragma unroll
      for (int kc = 0; kc < 2; ++kc)
        Ap[mt][kc] = *(const v8s*)&P[mt * 16 + lm][kc * 32 + quad * 8];
    #pragma unroll
    for (int nd = 0; nd < 2; ++nd)
      #pragma unroll
      for (int kc = 0; kc < 2; ++kc)
        Bv[nd][kc] = *(const v8s*)&Vt[nd * 16 + lm][kc * 32 + quad * 8];
    #pragma unroll
    for (int mt = 0; mt < 4; ++mt) {
      #pragma unroll
      for (int nd = 0; nd < 2; ++nd) {
        v4f O = (v4f)(0.f);
        O = __builtin_amdgcn_mfma_f32_16x16x32_bf16(Ap[mt][0], Bv[nd][0], O, 0, 0, 0);
        O = __builtin_amdgcn_mfma_f32_16x16x32_bf16(Ap[mt][1], Bv[nd][1], O, 0, 0, 0);
        #pragma unroll
        for (int r = 0; r < 4; ++r)
          P[mt * 16 + quad * 4 + r][nd * 16 + lm] = f2bf(O[r] * inv[mt][r]);
      }
    }
    // --- pack-store O into q columns ---
    #pragma unroll
    for (int part = 0; part < 4; ++part) {
      uint4 u = *(const uint4*)&P[lane][part * 8];
      *(uint4*)&Q[(rowbase + lane) * 768 + hoff + part * 8] = u;
    }
  }
}

// ---------------- attention: global time (pooled q, seq 256), bf16 in ----------------
__global__ __launch_bounds__(256) void attn3_k(const unsigned short* __restrict__ Q3,
                                               float* __restrict__ y3, int bf_base) {
  __shared__ float part[8][32];
  __shared__ float sqm[32];
  __shared__ float sp[256];
  __shared__ float sred[256];
  int bfl = blockIdx.x >> 3, h = blockIdx.x & 7;
  int tid = threadIdx.x;
  int tg = tid >> 5, d = tid & 31;
  const float scale = 0.17677669529663687f;
  int rowbase = bfl * 256;
  float s = 0.f;
  for (int t = tg * 32; t < tg * 32 + 32; ++t) s += bf2f(Q3[(size_t)(rowbase + t) * 768 + h * 32 + d]);
  part[tg][d] = s;
  __syncthreads();
  if (tid < 32) {
    float m = 0.f;
    for (int g = 0; g < 8; ++g) m += part[g][tid];
    sqm[tid] = m * (1.f / 256.f);
  }
  __syncthreads();
  {
    float dot = 0.f;
    const unsigned short* kp = &Q3[(size_t)(rowbase + tid) * 768 + 256 + h * 32];
    for (int dd = 0; dd < 32; ++dd) dot += sqm[dd] * bf2f(kp[dd]);
    sp[tid] = dot * scale;
    sred[tid] = sp[tid];
  }
  __syncthreads();
  for (int st = 128; st > 0; st >>= 1) { if (tid < st) sred[tid] = fmaxf(sred[tid], sred[tid + st]); __syncthreads(); }
  float mx = sred[0];
  __syncthreads();
  float e = expf(sp[tid] - mx);
  sred[tid] = e;
  __syncthreads();
  for (int st = 128; st > 0; st >>= 1) { if (tid < st) sred[tid] += sred[tid + st]; __syncthreads(); }
  float rinv = 1.f / sred[0];
  sp[tid] = e * rinv;
  __syncthreads();
  float acc = 0.f;
  for (int t = tg * 32; t < tg * 32 + 32; ++t)
    acc += sp[t] * bf2f(Q3[(size_t)(rowbase + t) * 768 + 512 + h * 32 + d]);
  part[tg][d] = acc;
  __syncthreads();
  if (tid < 32) {
    float o = 0.f;
    for (int g = 0; g < 8; ++g) o += part[g][tid];
    y3[(size_t)(bf_base + bfl) * 256 + h * 32 + tid] = o;
  }
}

// ---------------- LSA: local window 16 along T, bf16 in, o bf16 -> q cols ----------------
__global__ __launch_bounds__(256) void lsa_attn_k(unsigned short* __restrict__ Q4) {
  __shared__ __align__(16) float sX[16][772];
  __shared__ float sS[8][16][17];
  __shared__ float sInv[8][16];
  int bfl = blockIdx.x >> 4, w = blockIdx.x & 15;
  int tid = threadIdx.x;
  size_t rb = ((size_t)(bfl * 256 + w * 16)) * 768;
  for (int s = tid; s < 1536; s += 256) {
    int t = s / 96, c8 = (s - t * 96) * 8;
    unpack8(*(const uint4*)&Q4[rb + t * 768 + c8], &sX[t][c8]);
  }
  __syncthreads();
  const float scale = 0.17677669529663687f;
  #pragma unroll
  for (int rep = 0; rep < 8; ++rep) {
    int idx = tid + rep * 256;
    int h = idx >> 8, q = (idx >> 4) & 15, k = idx & 15;
    float dot = 0.f;
    const float* qp = &sX[q][h * 32];
    const float* kp = &sX[k][256 + h * 32];
    for (int d = 0; d < 32; ++d) dot += qp[d] * kp[d];
    sS[h][q][k] = dot * scale;
  }
  __syncthreads();
  if (tid < 128) {
    int h = tid >> 4, q = tid & 15;
    float mx = -1e30f;
    for (int k = 0; k < 16; ++k) mx = fmaxf(mx, sS[h][q][k]);
    float sum = 0.f;
    for (int k = 0; k < 16; ++k) { float e = expf(sS[h][q][k] - mx); sS[h][q][k] = e; sum += e; }
    sInv[h][q] = 1.f / sum;
  }
  __syncthreads();
  #pragma unroll
  for (int rep = 0; rep < 8; ++rep) {
    int idx = tid + rep * 256;
    int t = idx >> 7, c2 = (idx & 127) * 2;
    int h = c2 >> 5;
    float a0 = 0.f, a1 = 0.f;
    for (int k = 0; k < 16; ++k) {
      float p = sS[h][t][k];
      a0 += p * sX[k][512 + c2];
      a1 += p * sX[k][512 + c2 + 1];
    }
    float riv = sInv[h][t];
    *(unsigned*)&Q4[rb + t * 768 + c2] = packbf2(a0 * riv, a1 * riv);
  }
}

// ---------------- small GN / broadcast ----------------
__global__ void gn_rows_k(const float* __restrict__ src, float* __restrict__ dst, int total) {
  int s = blockIdx.x * 256 + threadIdx.x;
  if (s >= total) return;
  int base = s * 8;
  float4 a = *(const float4*)&src[base];
  float4 b = *(const float4*)&src[base + 4];
  float m = (a.x + a.y + a.z + a.w + b.x + b.y + b.z + b.w) * 0.125f;
  float q = (a.x * a.x + a.y * a.y + a.z * a.z + a.w * a.w +
             b.x * b.x + b.y * b.y + b.z * b.z + b.w * b.w) * 0.125f - m * m;
  float r = rsqrtf(q + 1e-5f);
  a.x = (a.x - m) * r; a.y = (a.y - m) * r; a.z = (a.z - m) * r; a.w = (a.w - m) * r;
  b.x = (b.x - m) * r; b.y = (b.y - m) * r; b.z = (b.z - m) * r; b.w = (b.w - m) * r;
  *(float4*)&dst[base] = a;
  *(float4*)&dst[base + 4] = b;
}

__global__ __launch_bounds__(256) void bcast_add_k(float* __restrict__ XT, const float* __restrict__ y3n,
                                                   const float* __restrict__ gate) {
  int i4 = blockIdx.x * 256 + threadIdx.x;
  int flat = i4 * 4;
  int r = flat >> 16, c = flat & 255;
  float g = gate[0];
  float4 v = ((float4*)XT)[i4];
  float4 a = *(const float4*)&y3n[r * 256 + c];
  v.x += g * a.x; v.y += g * a.y; v.z += g * a.z; v.w += g * a.w;
  ((float4*)XT)[i4] = v;
}

__global__ __launch_bounds__(256) void gn_stats_xt_k(const float* __restrict__ X, float* __restrict__ stats) {
  __shared__ float sbuf[8];
  int bx = blockIdx.x;
  int b = bx >> 11, g = (bx >> 6) & 31, f = bx & 63;
  size_t base = (size_t)(b * 64 + f) * 65536 + g * 8;
  float s = 0.f, ss = 0.f;
  for (int i = threadIdx.x; i < 2048; i += 256) {
    int t = i >> 3, c = i & 7;
    float v = X[base + t * 256 + c];
    s += v; ss += v * v;
  }
  blockReduce2(s, ss, sbuf);
  if (threadIdx.x == 0) { atomicAdd(&stats[b * 32 + g], s); atomicAdd(&stats[128 + b * 32 + g], ss); }
}

// ---------------- launch ----------------
extern "C" void kernel_launch(void* const* d_in, const int* in_sizes, int n_in,
                              void* d_out, int out_size, void* d_ws, size_t ws_size,
                              hipStream_t stream) {
  (void)in_sizes; (void)n_in; (void)out_size;
  const float* x        = (const float*)d_in[0];
  const float* temb     = (const float*)d_in[1];
  const float* conv1_w  = (const float*)d_in[2];
  const float* conv1_b  = (const float*)d_in[3];
  const float* conv2_w  = (const float*)d_in[4];
  const float* g_diff   = (const float*)d_in[5];
  const float* g_res    = (const float*)d_in[6];
  const float* g2       = (const float*)d_in[7];
  const float* g3       = (const float*)d_in[8];
  const float* qkv2_w   = (const float*)d_in[9];
  const float* qkv2_b   = (const float*)d_in[10];
  const float* out2_w   = (const float*)d_in[11];
  const float* qkv3_w   = (const float*)d_in[12];
  const float* qkv3_b   = (const float*)d_in[13];
  const float* out3_w   = (const float*)d_in[14];
  const float* lsa_qkv_w = (const float*)d_in[15];
  const float* lsa_out_w = (const float*)d_in[16];
  float* out = (float*)d_out;
  float* ws = (float*)d_ws;

  // adaptive chunking: pick largest chunk size that fits ws
  int NCHv = 4;
  {
    auto need = [](int nch) -> size_t {
      size_t rows = 65536 / nch;
      size_t uslots = rows * 512;
      if (uslots < 8388608) uslots = 8388608;
      return 4ull * ((size_t)NN + uslots + 950272 + 196864 + 256);
    };
    if (ws_size >= need(1)) NCHv = 1;
    else if (ws_size >= need(2)) NCHv = 2;
  }
  const size_t rows = 65536 / NCHv;

  float* W = ws;                                  // NN fp32 trunk
  float* U = ws + (size_t)NN;                     // union region
  unsigned short* XC  = (unsigned short*)U;       // NN bf16 (conv staging)
  unsigned short* QB  = (unsigned short*)U;       // rows*768 bf16 (qkv)
  unsigned short* O2B = (unsigned short*)(U + rows * 384);  // rows*256 bf16
  size_t uslots = rows * 512; if (uslots < 8388608) uslots = 8388608;
  float* WREG = U + uslots;
  unsigned short* WB1   = (unsigned short*)WREG;
  unsigned short* WB2   = WB1 + 589824;
  unsigned short* QKV2T = WB2 + 589824;
  unsigned short* OUT2T = QKV2T + 196608;
  unsigned short* QKV3T = OUT2T + 65536;
  unsigned short* LSAQT = QKV3T + 196608;
  unsigned short* LSAOT = LSAQT + 196608;
  float* Y3    = WREG + 950272;
  float* Y3O   = Y3 + 65536;
  float* Y3N   = Y3O + 65536;
  float* STATS = Y3N + 65536;
  float* D = out;                                 // d_out as scratch until final stage

  dim3 b256(256);
  convw_bf_k<<<2304, b256, 0, stream>>>(conv1_w, WB1);
  convw_bf_k<<<2304, b256, 0, stream>>>(conv2_w, WB2);
  matT_bf_k<<<768, b256, 0, stream>>>(qkv2_w, QKV2T, 768, 196608);
  matT_bf_k<<<256, b256, 0, stream>>>(out2_w, OUT2T, 256, 65536);
  matT_bf_k<<<768, b256, 0, stream>>>(qkv3_w, QKV3T, 768, 196608);
  matT_bf_k<<<768, b256, 0, stream>>>(lsa_qkv_w, LSAQT, 768, 196608);
  matT_bf_k<<<256, b256, 0, stream>>>(lsa_out_w, LSAOT, 256, 65536);

  // ---- residual block ----
  zero_stats_k<<<1, b256, 0, stream>>>(STATS);
  gn_stats_contig<<<1024, b256, 0, stream>>>(x, STATS);
  gn_apply_tr_k<<<16384, b256, 0, stream>>>(x, STATS, XC, 1e-6f);
  conv3x3_mfma_k<<<dim3(64, 8), b256, 0, stream>>>(XC, WB1, conv1_b, temb, g_diff, W, 1);
  zero_stats_k<<<1, b256, 0, stream>>>(STATS);
  gn_stats_contig<<<1024, b256, 0, stream>>>(W, STATS);
  gn_apply_tr_k<<<16384, b256, 0, stream>>>(W, STATS, XC, 1e-6f);
  conv3x3_mfma_k<<<dim3(64, 8), b256, 0, stream>>>(XC, WB2, nullptr, nullptr, nullptr, W, 0);
  zero_stats_k<<<1, b256, 0, stream>>>(STATS);
  gn_stats_contig<<<1024, b256, 0, stream>>>(W, STATS);
  gn_tr_resid_k<<<16384, b256, 0, stream>>>(W, x, STATS, g_res, D, 1e-6f);  // D = xf

  // ---- layer2: freq attention ----
  for (int c = 0; c < NCHv; ++c) {
    float* XFr = D + (size_t)c * rows * 256;
    gemm_af32_k<<<dim3(6, rows / 128), b256, 0, stream>>>(XFr, 256, QKV2T, qkv2_b, QB, 768, nullptr, 0, 0.f);
    attn2_mfma_k<<<rows / 64, b256, 0, stream>>>(QB);
    gemm_abf16_k<<<dim3(2, rows / 128), b256, 0, stream>>>(QB, 768, OUT2T, XFr, nullptr, 256, g2);
  }

  // ---- layer3: global time attention ----
  xf_to_xt_k<<<16384, b256, 0, stream>>>(D, W);   // W = xt
  for (int c = 0; c < NCHv; ++c) {
    const float* XTr = W + (size_t)c * rows * 256;
    gemm_af32_k<<<dim3(6, rows / 128), b256, 0, stream>>>(XTr, 256, QKV3T, qkv3_b, QB, 768, nullptr, 0, 0.f);
    attn3_k<<<(rows / 256) * 8, b256, 0, stream>>>(QB, Y3, c * (int)(rows / 256));
  }
  gemm_k<<<dim3(4, 4), b256, 0, stream>>>(Y3, 256, out3_w, 256, nullptr, Y3O, 256);
  gn_rows_k<<<32, b256, 0, stream>>>(Y3O, Y3N, 8192);
  bcast_add_k<<<16384, b256, 0, stream>>>(W, Y3N, g3);

  // ---- layer4: LSA ----
  zero_stats_k<<<1, b256, 0, stream>>>(STATS);
  gn_stats_xt_k<<<8192, b256, 0, stream>>>(W, STATS);
  for (int c = 0; c < NCHv; ++c) {
    const float* XTr = W + (size_t)c * rows * 256;
    gemm_af32_k<<<dim3(6, rows / 128), b256, 0, stream>>>(XTr, 256, LSAQT, nullptr, QB, 768,
                                                          STATS, (int)(c * rows), 1e-5f);
    lsa_attn_k<<<(rows / 256) * 16, b256, 0, stream>>>(QB);
    gemm_abf16_k<<<dim3(2, rows / 128), b256, 0, stream>>>(QB, 768, LSAOT, nullptr, O2B, 256, nullptr);
    final_out_k<<<(rows / 256) * 64, b256, 0, stream>>>(W, O2B, out, c * (int)(rows / 256));
  }
}

// Round 6
// 1094.546 us; speedup vs baseline: 4.9003x; 1.0196x over previous
//
#include <hip/hip_runtime.h>

#define NN 16777216   // 4*256*64*256
#define CC 256
#define FF 64
#define TT 256

typedef short v8s __attribute__((ext_vector_type(8)));
typedef float v4f __attribute__((ext_vector_type(4)));

__device__ __forceinline__ unsigned short f2bf(float f) {
  unsigned u = __float_as_uint(f);
  u += 0x7fff + ((u >> 16) & 1);
  return (unsigned short)(u >> 16);
}
__device__ __forceinline__ float bf2f(unsigned short h) {
  return __uint_as_float(((unsigned)h) << 16);
}
__device__ __forceinline__ unsigned packbf2(float a, float b) {
  return (unsigned)f2bf(a) | ((unsigned)f2bf(b) << 16);
}
__device__ __forceinline__ void unpack8(uint4 u, float* d) {
  d[0] = __uint_as_float(u.x << 16); d[1] = __uint_as_float(u.x & 0xffff0000u);
  d[2] = __uint_as_float(u.y << 16); d[3] = __uint_as_float(u.y & 0xffff0000u);
  d[4] = __uint_as_float(u.z << 16); d[5] = __uint_as_float(u.z & 0xffff0000u);
  d[6] = __uint_as_float(u.w << 16); d[7] = __uint_as_float(u.w & 0xffff0000u);
}

// ---------------- helpers ----------------
__device__ __forceinline__ void blockReduce2(float& a, float& b, float* sbuf) {
  #pragma unroll
  for (int off = 32; off > 0; off >>= 1) {
    a += __shfl_down(a, off, 64);
    b += __shfl_down(b, off, 64);
  }
  int w = threadIdx.x >> 6;
  if ((threadIdx.x & 63) == 0) { sbuf[w] = a; sbuf[4 + w] = b; }
  __syncthreads();
  if (threadIdx.x == 0) {
    a = sbuf[0] + sbuf[1] + sbuf[2] + sbuf[3];
    b = sbuf[4] + sbuf[5] + sbuf[6] + sbuf[7];
  }
}

// ---------------- combined weight prep + stats zero (one dispatch) ----------------
__global__ void prep_all_k(const float* __restrict__ c1w, const float* __restrict__ c2w,
    const float* __restrict__ q2w, const float* __restrict__ o2w, const float* __restrict__ q3w,
    const float* __restrict__ lqw, const float* __restrict__ low,
    unsigned short* __restrict__ WB1, unsigned short* __restrict__ WB2,
    unsigned short* __restrict__ Q2T, unsigned short* __restrict__ O2T,
    unsigned short* __restrict__ Q3T, unsigned short* __restrict__ LQT,
    unsigned short* __restrict__ LOT, float* __restrict__ stats) {
  long s = (long)blockIdx.x * 256 + threadIdx.x;
  if (s < 1024) { stats[s] = 0.f; return; }
  s -= 1024;
  if (s < 589824) {
    int co = (int)(s / 2304), r = (int)(s % 2304);
    int ci = r / 9, tap = r % 9;
    WB1[(tap * 256 + co) * 256 + ci] = f2bf(c1w[s]);
    return;
  }
  s -= 589824;
  if (s < 589824) {
    int co = (int)(s / 2304), r = (int)(s % 2304);
    int ci = r / 9, tap = r % 9;
    WB2[(tap * 256 + co) * 256 + ci] = f2bf(c2w[s]);
    return;
  }
  s -= 589824;
  if (s < 196608) { int k = (int)(s / 768), n = (int)(s % 768); Q2T[n * 256 + k] = f2bf(q2w[s]); return; }
  s -= 196608;
  if (s < 65536)  { int k = (int)(s / 256), n = (int)(s % 256); O2T[n * 256 + k] = f2bf(o2w[s]); return; }
  s -= 65536;
  if (s < 196608) { int k = (int)(s / 768), n = (int)(s % 768); Q3T[n * 256 + k] = f2bf(q3w[s]); return; }
  s -= 196608;
  if (s < 196608) { int k = (int)(s / 768), n = (int)(s % 768); LQT[n * 256 + k] = f2bf(lqw[s]); return; }
  s -= 196608;
  if (s < 65536)  { int k = (int)(s / 256), n = (int)(s % 256); LOT[n * 256 + k] = f2bf(low[s]); return; }
}

// ---------------- GroupNorm stats (NCHW contiguous: 131072/group) ----------------
__global__ __launch_bounds__(256) void gn_stats_contig(const float* __restrict__ src, float* __restrict__ stats) {
  __shared__ float sbuf[8];
  int grp = blockIdx.x >> 3, chunk = blockIdx.x & 7;
  const float4* p = (const float4*)src + grp * 32768 + chunk * 4096;
  float s = 0.f, ss = 0.f;
  for (int i = threadIdx.x; i < 4096; i += 256) {
    float4 v = p[i];
    s += v.x + v.y + v.z + v.w;
    ss += v.x * v.x + v.y * v.y + v.z * v.z + v.w * v.w;
  }
  blockReduce2(s, ss, sbuf);
  if (threadIdx.x == 0) { atomicAdd(&stats[grp], s); atomicAdd(&stats[128 + grp], ss); }
}

// GN apply + transpose to bf16 [b][f][t][ci]
__global__ __launch_bounds__(256) void gn_apply_tr_k(const float* __restrict__ src,
    const float* __restrict__ stats, unsigned short* __restrict__ XC, float eps) {
  __shared__ float sT[32][33];
  int bx = blockIdx.x;
  int r = bx >> 6;
  int c0 = ((bx >> 3) & 7) * 32;
  int t0 = (bx & 7) * 32;
  int b = r >> 6, f = r & 63;
  int tl = threadIdx.x & 31, tr = threadIdx.x >> 5;
  #pragma unroll
  for (int i = 0; i < 4; ++i) {
    int c = c0 + tr + i * 8;
    int grp = b * 32 + (c >> 3);
    float mean = stats[grp] * (1.f / 131072.f);
    float var = stats[128 + grp] * (1.f / 131072.f) - mean * mean;
    float rv = rsqrtf(var + eps);
    float v = src[((b * 256 + c) * 64 + f) * 256 + t0 + tl];
    sT[tr + i * 8][tl] = (v - mean) * rv;
  }
  __syncthreads();
  #pragma unroll
  for (int i = 0; i < 4; ++i) {
    int t = t0 + tr + i * 8;
    XC[(((size_t)(b * 64 + f)) * 256 + t) * 256 + c0 + tl] = f2bf(sT[tl][tr + i * 8]);
  }
}

// GN apply + gated residual + transpose to XF fp32 [(b*256+t)*64+f][c]
__global__ __launch_bounds__(256) void gn_tr_resid_k(const float* __restrict__ h,
    const float* __restrict__ x, const float* __restrict__ stats,
    const float* __restrict__ gate, float* __restrict__ XF, float eps) {
  __shared__ float sT[32][33];
  int bx = blockIdx.x;
  int r = bx >> 6;
  int c0 = ((bx >> 3) & 7) * 32;
  int t0 = (bx & 7) * 32;
  int b = r >> 6, f = r & 63;
  int tl = threadIdx.x & 31, tr = threadIdx.x >> 5;
  float g = gate[0];
  #pragma unroll
  for (int i = 0; i < 4; ++i) {
    int c = c0 + tr + i * 8;
    int grp = b * 32 + (c >> 3);
    float mean = stats[grp] * (1.f / 131072.f);
    float var = stats[128 + grp] * (1.f / 131072.f) - mean * mean;
    float rv = rsqrtf(var + eps);
    int idx = ((b * 256 + c) * 64 + f) * 256 + t0 + tl;
    sT[tr + i * 8][tl] = x[idx] + g * (h[idx] - mean) * rv;
  }
  __syncthreads();
  #pragma unroll
  for (int i = 0; i < 4; ++i) {
    int t = t0 + tr + i * 8;
    XF[(((size_t)(b * 256 + t)) * 64 + f) * 256 + c0 + tl] = sT[tl][tr + i * 8];
  }
}

// ---------------- conv 3x3 via MFMA; fused output GN-stats ----------------
// XC bf16 [b][f][t][ci]; wb bf16 [tap][co][ci]; out fp32 [b][co][f][t]; ostats += per-(b,group) s/ss
__global__ __launch_bounds__(256, 2) void conv3x3_mfma_k(const unsigned short* __restrict__ XC,
    const unsigned short* __restrict__ wb, const float* __restrict__ bias,
    const float* __restrict__ temb, const float* __restrict__ gd,
    float* __restrict__ out, float* __restrict__ ostats, int mode) {
  __shared__ __align__(16) unsigned short sIn[258][40];
  __shared__ __align__(16) unsigned short sW[3][128][40];
  int f  = blockIdx.x;
  int b  = blockIdx.y >> 1;
  int co0 = (blockIdx.y & 1) * 128;
  int tid = threadIdx.x;
  int wave = tid >> 6, lane = tid & 63;
  int lm = lane & 15, quad = lane >> 4;
  int w64 = wave * 64;
  v4f acc[4][8];
  #pragma unroll
  for (int i = 0; i < 4; ++i)
    #pragma unroll
    for (int j = 0; j < 8; ++j) acc[i][j] = (v4f)(0.f);

  for (int ci0 = 0; ci0 < 256; ci0 += 32) {
    for (int df = 0; df < 3; ++df) {
      __syncthreads();
      // stage one input f-row (258 t x 32 ci)
      for (int s = tid; s < 1032; s += 256) {
        int tl = s >> 2, part = s & 3;
        int fi = f + df - 1, tg = tl - 1;
        uint4 val = make_uint4(0, 0, 0, 0);
        if (fi >= 0 && fi < 64 && tg >= 0 && tg < 256)
          val = *(const uint4*)&XC[(((size_t)(b * 64 + fi)) * 256 + tg) * 256 + ci0 + part * 8];
        *(uint4*)&sIn[tl][part * 8] = val;
      }
      // stage 3 taps of weights (128 co x 32 ci each)
      for (int s = tid; s < 1536; s += 256) {
        int tap3 = s >> 9, r = s & 511;
        int co = r >> 2, part = r & 3;
        *(uint4*)&sW[tap3][co][part * 8] =
            *(const uint4*)&wb[((size_t)((df * 3 + tap3) * 256) + co0 + co) * 256 + ci0 + part * 8];
      }
      __syncthreads();
      #pragma unroll
      for (int dt = 0; dt < 3; ++dt) {
        v8s A[4];
        #pragma unroll
        for (int mt = 0; mt < 4; ++mt)
          A[mt] = *(const v8s*)&sIn[w64 + mt * 16 + lm + dt][quad * 8];
        #pragma unroll
        for (int nt = 0; nt < 8; ++nt) {
          v8s B = *(const v8s*)&sW[dt][nt * 16 + lm][quad * 8];
          #pragma unroll
          for (int mt = 0; mt < 4; ++mt)
            acc[mt][nt] = __builtin_amdgcn_mfma_f32_16x16x32_bf16(A[mt], B, acc[mt][nt], 0, 0, 0);
        }
      }
    }
  }
  __syncthreads();   // done reading sIn/sW; reuse sIn as float scratch
  float* sStat = (float*)sIn;     // [wave][nt][lm][2]
  float gdv = mode ? gd[0] : 0.f;
  float sch, qch;
  #pragma unroll
  for (int nt = 0; nt < 8; ++nt) {
    int co = co0 + nt * 16 + lm;
    float bb = 0.f;
    if (mode) bb = bias[co] + gdv * temb[b * 256 + co];
    sch = 0.f; qch = 0.f;
    #pragma unroll
    for (int mt = 0; mt < 4; ++mt) {
      int t = w64 + mt * 16 + quad * 4;
      float v0 = acc[mt][nt][0] + bb, v1 = acc[mt][nt][1] + bb;
      float v2 = acc[mt][nt][2] + bb, v3 = acc[mt][nt][3] + bb;
      if (mode) {
        v0 = v0 / (1.f + expf(-v0)); v1 = v1 / (1.f + expf(-v1));
        v2 = v2 / (1.f + expf(-v2)); v3 = v3 / (1.f + expf(-v3));
      }
      float4 o; o.x = v0; o.y = v1; o.z = v2; o.w = v3;
      *(float4*)&out[(((size_t)b * 256 + co) * 64 + f) * 256 + t] = o;
      sch += v0 + v1 + v2 + v3;
      qch += v0 * v0 + v1 * v1 + v2 * v2 + v3 * v3;
    }
    // reduce across quads (same channel, different t)
    sch += __shfl_xor(sch, 16); qch += __shfl_xor(qch, 16);
    sch += __shfl_xor(sch, 32); qch += __shfl_xor(qch, 32);
    if (quad == 0) {
      sStat[((wave * 8 + nt) * 16 + lm) * 2]     = sch;
      sStat[((wave * 8 + nt) * 16 + lm) * 2 + 1] = qch;
    }
  }
  __syncthreads();
  if (tid < 128) {
    int c = tid;                     // channel within block = nt*16+lm
    int nt = c >> 4, lmm = c & 15;
    float s = 0.f, q = 0.f;
    #pragma unroll
    for (int w = 0; w < 4; ++w) {
      s += sStat[((w * 8 + nt) * 16 + lmm) * 2];
      q += sStat[((w * 8 + nt) * 16 + lmm) * 2 + 1];
    }
    s += __shfl_xor(s, 1); q += __shfl_xor(q, 1);
    s += __shfl_xor(s, 2); q += __shfl_xor(q, 2);
    s += __shfl_xor(s, 4); q += __shfl_xor(q, 4);
    if ((c & 7) == 0) {
      int g = (co0 + c) >> 3;
      atomicAdd(&ostats[b * 32 + g], s);
      atomicAdd(&ostats[128 + b * 32 + g], q);
    }
  }
}

// ---------------- MFMA GEMM: Cb bf16 [M,N] = gn?(A fp32 [M,256]) @ B (+bias) ----------------
__global__ __launch_bounds__(256) void gemm_af32_k(const float* __restrict__ A, int lda,
    const unsigned short* __restrict__ BT, const float* __restrict__ bias,
    unsigned short* __restrict__ Cb, int ldc,
    const float* __restrict__ gstats, int growbase, float eps) {
  __shared__ __align__(16) unsigned short sA[128][40];
  __shared__ __align__(16) unsigned short sB[128][40];
  int n0 = blockIdx.x * 128, m0 = blockIdx.y * 128;
  int tid = threadIdx.x;
  int wave = tid >> 6, lane = tid & 63;
  int wm = wave >> 1, wn = wave & 1;
  int lm = lane & 15, quad = lane >> 4;
  v4f acc[4][4];
  #pragma unroll
  for (int i = 0; i < 4; ++i)
    #pragma unroll
    for (int j = 0; j < 4; ++j) acc[i][j] = (v4f)(0.f);

  for (int k0 = 0; k0 < 256; k0 += 32) {
    __syncthreads();
    #pragma unroll
    for (int i = 0; i < 4; ++i) {
      int s = tid + i * 256;
      int row = s >> 3, k4 = s & 7;
      float4 av = *(const float4*)&A[(size_t)(m0 + row) * lda + k0 + k4 * 4];
      if (gstats) {
        int grp = ((growbase + m0 + row) >> 14) * 32 + ((k0 + k4 * 4) >> 3);
        float mean = gstats[grp] * (1.f / 131072.f);
        float var = gstats[128 + grp] * (1.f / 131072.f) - mean * mean;
        float rr = rsqrtf(var + eps);
        av.x = (av.x - mean) * rr; av.y = (av.y - mean) * rr;
        av.z = (av.z - mean) * rr; av.w = (av.w - mean) * rr;
      }
      *(uint2*)&sA[row][k4 * 4] = make_uint2(packbf2(av.x, av.y), packbf2(av.z, av.w));
    }
    #pragma unroll
    for (int i = 0; i < 2; ++i) {
      int s = tid + i * 256;
      int n = s >> 2, part = s & 3;
      *(uint4*)&sB[n][part * 8] = *(const uint4*)&BT[(size_t)(n0 + n) * 256 + k0 + part * 8];
    }
    __syncthreads();
    v8s Af[4];
    #pragma unroll
    for (int mt = 0; mt < 4; ++mt)
      Af[mt] = *(const v8s*)&sA[wm * 64 + mt * 16 + lm][quad * 8];
    #pragma unroll
    for (int nt = 0; nt < 4; ++nt) {
      v8s Bf = *(const v8s*)&sB[wn * 64 + nt * 16 + lm][quad * 8];
      #pragma unroll
      for (int mt = 0; mt < 4; ++mt)
        acc[mt][nt] = __builtin_amdgcn_mfma_f32_16x16x32_bf16(Af[mt], Bf, acc[mt][nt], 0, 0, 0);
    }
  }
  #pragma unroll
  for (int nt = 0; nt < 4; ++nt) {
    int col = n0 + wn * 64 + nt * 16 + lm;
    float bb = bias ? bias[col] : 0.f;
    #pragma unroll
    for (int mt = 0; mt < 4; ++mt) {
      int row = m0 + wm * 64 + mt * 16 + quad * 4;
      #pragma unroll
      for (int r = 0; r < 4; ++r)
        Cb[(size_t)(row + r) * ldc + col] = f2bf(acc[mt][nt][r] + bb);
    }
  }
}

// ---------------- MFMA GEMM, A bf16: either bf16 C out, or fused rowGN+gate+add into xf ----------------
__global__ __launch_bounds__(256) void gemm_abf16_k(const unsigned short* __restrict__ A, int lda,
    const unsigned short* __restrict__ BT, float* __restrict__ xf,
    unsigned short* __restrict__ Cb, int ldc, const float* __restrict__ gate) {
  __shared__ __align__(16) unsigned short sA[128][40];
  __shared__ __align__(16) unsigned short sB[128][40];
  int n0 = blockIdx.x * 128, m0 = blockIdx.y * 128;
  int tid = threadIdx.x;
  int wave = tid >> 6, lane = tid & 63;
  int wm = wave >> 1, wn = wave & 1;
  int lm = lane & 15, quad = lane >> 4;
  v4f acc[4][4];
  #pragma unroll
  for (int i = 0; i < 4; ++i)
    #pragma unroll
    for (int j = 0; j < 4; ++j) acc[i][j] = (v4f)(0.f);

  for (int k0 = 0; k0 < 256; k0 += 32) {
    __syncthreads();
    #pragma unroll
    for (int i = 0; i < 2; ++i) {
      int s = tid + i * 256;
      int row = s >> 2, part = s & 3;
      *(uint4*)&sA[row][part * 8] = *(const uint4*)&A[(size_t)(m0 + row) * lda + k0 + part * 8];
      *(uint4*)&sB[row][part * 8] = *(const uint4*)&BT[(size_t)(n0 + row) * 256 + k0 + part * 8];
    }
    __syncthreads();
    v8s Af[4];
    #pragma unroll
    for (int mt = 0; mt < 4; ++mt)
      Af[mt] = *(const v8s*)&sA[wm * 64 + mt * 16 + lm][quad * 8];
    #pragma unroll
    for (int nt = 0; nt < 4; ++nt) {
      v8s Bf = *(const v8s*)&sB[wn * 64 + nt * 16 + lm][quad * 8];
      #pragma unroll
      for (int mt = 0; mt < 4; ++mt)
        acc[mt][nt] = __builtin_amdgcn_mfma_f32_16x16x32_bf16(Af[mt], Bf, acc[mt][nt], 0, 0, 0);
    }
  }
  if (xf) {
    float g = gate[0];
    #pragma unroll
    for (int mt = 0; mt < 4; ++mt) {
      int rowb = m0 + wm * 64 + mt * 16 + quad * 4;
      #pragma unroll
      for (int r = 0; r < 4; ++r) {
        #pragma unroll
        for (int nt = 0; nt < 4; ++nt) {
          float v = acc[mt][nt][r];
          float s = v, q = v * v;
          s += __shfl_xor(s, 1); q += __shfl_xor(q, 1);
          s += __shfl_xor(s, 2); q += __shfl_xor(q, 2);
          s += __shfl_xor(s, 4); q += __shfl_xor(q, 4);
          float m = s * 0.125f;
          float var = q * 0.125f - m * m;
          float norm = (v - m) * rsqrtf(var + 1e-5f);
          int col = n0 + wn * 64 + nt * 16 + lm;
          size_t idx = (size_t)(rowb + r) * 256 + col;
          xf[idx] += g * norm;
        }
      }
    }
  } else {
    #pragma unroll
    for (int nt = 0; nt < 4; ++nt) {
      int col = n0 + wn * 64 + nt * 16 + lm;
      #pragma unroll
      for (int mt = 0; mt < 4; ++mt) {
        int row = m0 + wm * 64 + mt * 16 + quad * 4;
        #pragma unroll
        for (int r = 0; r < 4; ++r)
          Cb[(size_t)(row + r) * ldc + col] = f2bf(acc[mt][nt][r]);
      }
    }
  }
}

// ---------------- fp32 GEMM (tiny out3 matmul) ----------------
__global__ __launch_bounds__(256) void gemm_k(const float* __restrict__ A, int lda,
    const float* __restrict__ Bm, int N, const float* __restrict__ bias,
    float* __restrict__ Cm, int ldc) {
  __shared__ __align__(16) float sA[16][64];
  __shared__ __align__(16) float sB[16][64];
  int n0 = blockIdx.x * 64, m0 = blockIdx.y * 64;
  int tid = threadIdx.x;
  int tx = tid & 15, ty = tid >> 4;
  int arow = m0 + (tid >> 2), acol = (tid & 3) * 4;
  int brow = tid >> 4, bcol = (tid & 15) * 4;
  float acc[4][4] = {};
  for (int k0 = 0; k0 < 256; k0 += 16) {
    __syncthreads();
    float4 av = *(const float4*)&A[(size_t)arow * lda + k0 + acol];
    sA[acol + 0][tid >> 2] = av.x;
    sA[acol + 1][tid >> 2] = av.y;
    sA[acol + 2][tid >> 2] = av.z;
    sA[acol + 3][tid >> 2] = av.w;
    *(float4*)&sB[brow][bcol] = *(const float4*)&Bm[(k0 + brow) * N + n0 + bcol];
    __syncthreads();
    #pragma unroll
    for (int kk = 0; kk < 16; ++kk) {
      float4 a = *(const float4*)&sA[kk][ty * 4];
      float4 b = *(const float4*)&sB[kk][tx * 4];
      float aa[4] = {a.x, a.y, a.z, a.w};
      float bb[4] = {b.x, b.y, b.z, b.w};
      #pragma unroll
      for (int i = 0; i < 4; ++i)
        #pragma unroll
        for (int j = 0; j < 4; ++j)
          acc[i][j] += aa[i] * bb[j];
    }
  }
  #pragma unroll
  for (int i = 0; i < 4; ++i)
    #pragma unroll
    for (int j = 0; j < 4; ++j) {
      int n = n0 + tx * 4 + j;
      float v = acc[i][j];
      if (bias) v += bias[n];
      Cm[(size_t)(m0 + ty * 4 + i) * ldc + n] = v;
    }
}

// ---------------- transposes ----------------
__global__ __launch_bounds__(256) void xf_to_xt_k(const float* __restrict__ XF, float* __restrict__ XT) {
  int rowid = blockIdx.x * 4 + (threadIdx.x >> 6);
  int lane = threadIdx.x & 63;
  int b = rowid >> 14, f = (rowid >> 8) & 63, t = rowid & 255;
  int src = ((b * TT + t) * FF + f) * CC + lane * 4;
  int dst = rowid * CC + lane * 4;
  *(float4*)&XT[dst] = *(const float4*)&XF[src];
}

// out[b][c][f][t] = XT[rg][t][c] + bf2f(O2b[rl][t][c])
__global__ __launch_bounds__(256) void final_out_k(const float* __restrict__ XT,
    const unsigned short* __restrict__ O2b, float* __restrict__ out, int rbase) {
  __shared__ float sT[32][33];
  int bx = blockIdx.x;
  int rl = bx >> 6;
  int t0 = ((bx >> 3) & 7) * 32;
  int c0 = (bx & 7) * 32;
  int rg = rbase + rl;
  int b = rg >> 6, f = rg & 63;
  int tc = threadIdx.x & 31, tr = threadIdx.x >> 5;
  #pragma unroll
  for (int i = 0; i < 4; ++i) {
    int t = t0 + tr + i * 8;
    sT[tr + i * 8][tc] = XT[(size_t)rg * 65536 + t * 256 + c0 + tc]
                       + bf2f(O2b[(size_t)rl * 65536 + t * 256 + c0 + tc]);
  }
  __syncthreads();
  #pragma unroll
  for (int i = 0; i < 4; ++i) {
    int c = c0 + tr + i * 8;
    out[((b * CC + c) * FF + f) * TT + t0 + tc] = sT[tc][tr + i * 8];
  }
}

// ---------------- attention: frequency axis (seq 64) via MFMA, in-place y -> q cols ----------------
__global__ __launch_bounds__(256) void attn2_mfma_k(unsigned short* __restrict__ Q) {
  __shared__ __align__(16) unsigned short sP[4][64][72];
  __shared__ __align__(16) unsigned short sVt[4][32][72];
  int bt = blockIdx.x;
  int tid = threadIdx.x;
  int wave = tid >> 6, lane = tid & 63;
  int lm = lane & 15, quad = lane >> 4;
  const float scale = 0.17677669529663687f;
  size_t rowbase = (size_t)bt * 64;
  unsigned short (*P)[72] = sP[wave];
  unsigned short (*Vt)[72] = sVt[wave];
  #pragma unroll
  for (int hh = 0; hh < 2; ++hh) {
    int h = wave * 2 + hh;
    int hoff = h * 32;
    v8s Af[4], Bf[4];
    #pragma unroll
    for (int mt = 0; mt < 4; ++mt)
      Af[mt] = *(const v8s*)&Q[(rowbase + mt * 16 + lm) * 768 + hoff + quad * 8];
    #pragma unroll
    for (int nt = 0; nt < 4; ++nt)
      Bf[nt] = *(const v8s*)&Q[(rowbase + nt * 16 + lm) * 768 + 256 + hoff + quad * 8];
    v4f S[4][4];
    #pragma unroll
    for (int mt = 0; mt < 4; ++mt)
      #pragma unroll
      for (int nt = 0; nt < 4; ++nt)
        S[mt][nt] = __builtin_amdgcn_mfma_f32_16x16x32_bf16(Af[mt], Bf[nt], (v4f)(0.f), 0, 0, 0);
    #pragma unroll
    for (int part = 0; part < 4; ++part) {
      uint4 u = *(const uint4*)&Q[(rowbase + lane) * 768 + 512 + hoff + part * 8];
      unsigned short* up = (unsigned short*)&u;
      #pragma unroll
      for (int j = 0; j < 8; ++j) Vt[part * 8 + j][lane] = up[j];
    }
    float inv[4][4];
    #pragma unroll
    for (int mt = 0; mt < 4; ++mt) {
      #pragma unroll
      for (int r = 0; r < 4; ++r) {
        float v0 = S[mt][0][r] * scale, v1 = S[mt][1][r] * scale;
        float v2 = S[mt][2][r] * scale, v3 = S[mt][3][r] * scale;
        float mx = fmaxf(fmaxf(v0, v1), fmaxf(v2, v3));
        mx = fmaxf(mx, __shfl_xor(mx, 1));
        mx = fmaxf(mx, __shfl_xor(mx, 2));
        mx = fmaxf(mx, __shfl_xor(mx, 4));
        mx = fmaxf(mx, __shfl_xor(mx, 8));
        float e0 = __expf(v0 - mx), e1 = __expf(v1 - mx);
        float e2 = __expf(v2 - mx), e3 = __expf(v3 - mx);
        float sm = e0 + e1 + e2 + e3;
        sm += __shfl_xor(sm, 1);
        sm += __shfl_xor(sm, 2);
        sm += __shfl_xor(sm, 4);
        sm += __shfl_xor(sm, 8);
        inv[mt][r] = 1.f / sm;
        int row = mt * 16 + quad * 4 + r;
        P[row][lm]      = f2bf(e0);
        P[row][16 + lm] = f2bf(e1);
        P[row][32 + lm] = f2bf(e2);
        P[row][48 + lm] = f2bf(e3);
      }
    }
    v8s Ap[4][2], Bv[2][2];
    #pragma unroll
    for (int mt = 0; mt < 4; ++mt)
      #pragma unroll
      for (int kc = 0; kc < 2; ++kc)
        Ap[mt][kc] = *(const v8s*)&P[mt * 16 + lm][kc * 32 + quad * 8];
    #pragma unroll
    for (int nd = 0; nd < 2; ++nd)
      #pragma unroll
      for (int kc = 0; kc < 2; ++kc)
        Bv[nd][kc] = *(const v8s*)&Vt[nd * 16 + lm][kc * 32 + quad * 8];
    #pragma unroll
    for (int mt = 0; mt < 4; ++mt) {
      #pragma unroll
      for (int nd = 0; nd < 2; ++nd) {
        v4f O = (v4f)(0.f);
        O = __builtin_amdgcn_mfma_f32_16x16x32_bf16(Ap[mt][0], Bv[nd][0], O, 0, 0, 0);
        O = __builtin_amdgcn_mfma_f32_16x16x32_bf16(Ap[mt][1], Bv[nd][1], O, 0, 0, 0);
        #pragma unroll
        for (int r = 0; r < 4; ++r)
          P[mt * 16 + quad * 4 + r][nd * 16 + lm] = f2bf(O[r] * inv[mt][r]);
      }
    }
    #pragma unroll
    for (int part = 0; part < 4; ++part) {
      uint4 u = *(const uint4*)&P[lane][part * 8];
      *(uint4*)&Q[(rowbase + lane) * 768 + hoff + part * 8] = u;
    }
  }
}

// ---------------- attention: global time (pooled q, seq 256), vectorized ----------------
__global__ __launch_bounds__(256) void attn3_k(const unsigned short* __restrict__ Q3,
                                               float* __restrict__ y3, int bf_base) {
  __shared__ float sQp[64][33];
  __shared__ float sqm[32];
  __shared__ float sp[256];
  __shared__ float sred[256];
  int bfl = blockIdx.x >> 3, h = blockIdx.x & 7;
  int tid = threadIdx.x;
  int tq = tid >> 2, c4 = tid & 3;
  int d8 = c4 * 8;
  const float scale = 0.17677669529663687f;
  size_t rowbase = (size_t)bfl * 256;
  // ---- q mean over t ----
  {
    float a[8] = {};
    #pragma unroll
    for (int i = 0; i < 4; ++i) {
      int t = i * 64 + tq;
      float v[8];
      unpack8(*(const uint4*)&Q3[(rowbase + t) * 768 + h * 32 + d8], v);
      #pragma unroll
      for (int j = 0; j < 8; ++j) a[j] += v[j];
    }
    #pragma unroll
    for (int j = 0; j < 8; ++j) sQp[tq][d8 + j] = a[j];
  }
  __syncthreads();
  if (tid < 32) {
    float m = 0.f;
    for (int g = 0; g < 64; ++g) m += sQp[g][tid];
    sqm[tid] = m * (1.f / 256.f);
  }
  __syncthreads();
  // ---- k . qm ----
  {
    float dot = 0.f;
    #pragma unroll
    for (int p = 0; p < 4; ++p) {
      float v[8];
      unpack8(*(const uint4*)&Q3[(rowbase + tid) * 768 + 256 + h * 32 + p * 8], v);
      #pragma unroll
      for (int j = 0; j < 8; ++j) dot += sqm[p * 8 + j] * v[j];
    }
    sp[tid] = dot * scale;
    sred[tid] = sp[tid];
  }
  __syncthreads();
  for (int st = 128; st > 0; st >>= 1) { if (tid < st) sred[tid] = fmaxf(sred[tid], sred[tid + st]); __syncthreads(); }
  float mx = sred[0];
  __syncthreads();
  float e = expf(sp[tid] - mx);
  sred[tid] = e;
  __syncthreads();
  for (int st = 128; st > 0; st >>= 1) { if (tid < st) sred[tid] += sred[tid + st]; __syncthreads(); }
  float rinv = 1.f / sred[0];
  sp[tid] = e * rinv;
  __syncthreads();
  // ---- weighted V sum ----
  {
    float a[8] = {};
    #pragma unroll
    for (int i = 0; i < 4; ++i) {
      int t = i * 64 + tq;
      float w = sp[t];
      float v[8];
      unpack8(*(const uint4*)&Q3[(rowbase + t) * 768 + 512 + h * 32 + d8], v);
      #pragma unroll
      for (int j = 0; j < 8; ++j) a[j] += w * v[j];
    }
    #pragma unroll
    for (int j = 0; j < 8; ++j) sQp[tq][d8 + j] = a[j];
  }
  __syncthreads();
  if (tid < 32) {
    float o = 0.f;
    for (int g = 0; g < 64; ++g) o += sQp[g][tid];
    y3[(size_t)(bf_base + bfl) * 256 + h * 32 + tid] = o;
  }
}

// ---------------- LSA: local window 16 along T, bf16 in, o bf16 -> q cols ----------------
__global__ __launch_bounds__(256) void lsa_attn_k(unsigned short* __restrict__ Q4) {
  __shared__ __align__(16) float sX[16][772];
  __shared__ float sS[8][16][17];
  __shared__ float sInv[8][16];
  int bfl = blockIdx.x >> 4, w = blockIdx.x & 15;
  int tid = threadIdx.x;
  size_t rb = ((size_t)(bfl * 256 + w * 16)) * 768;
  for (int s = tid; s < 1536; s += 256) {
    int t = s / 96, c8 = (s - t * 96) * 8;
    unpack8(*(const uint4*)&Q4[rb + t * 768 + c8], &sX[t][c8]);
  }
  __syncthreads();
  const float scale = 0.17677669529663687f;
  #pragma unroll
  for (int rep = 0; rep < 8; ++rep) {
    int idx = tid + rep * 256;
    int h = idx >> 8, q = (idx >> 4) & 15, k = idx & 15;
    float dot = 0.f;
    const float* qp = &sX[q][h * 32];
    const float* kp = &sX[k][256 + h * 32];
    for (int d = 0; d < 32; ++d) dot += qp[d] * kp[d];
    sS[h][q][k] = dot * scale;
  }
  __syncthreads();
  if (tid < 128) {
    int h = tid >> 4, q = tid & 15;
    float mx = -1e30f;
    for (int k = 0; k < 16; ++k) mx = fmaxf(mx, sS[h][q][k]);
    float sum = 0.f;
    for (int k = 0; k < 16; ++k) { float e = expf(sS[h][q][k] - mx); sS[h][q][k] = e; sum += e; }
    sInv[h][q] = 1.f / sum;
  }
  __syncthreads();
  #pragma unroll
  for (int rep = 0; rep < 8; ++rep) {
    int idx = tid + rep * 256;
    int t = idx >> 7, c2 = (idx & 127) * 2;
    int h = c2 >> 5;
    float a0 = 0.f, a1 = 0.f;
    for (int k = 0; k < 16; ++k) {
      float p = sS[h][t][k];
      a0 += p * sX[k][512 + c2];
      a1 += p * sX[k][512 + c2 + 1];
    }
    float riv = sInv[h][t];
    *(unsigned*)&Q4[rb + t * 768 + c2] = packbf2(a0 * riv, a1 * riv);
  }
}

// ---------------- small GN / broadcast ----------------
__global__ void gn_rows_k(const float* __restrict__ src, float* __restrict__ dst, int total) {
  int s = blockIdx.x * 256 + threadIdx.x;
  if (s >= total) return;
  int base = s * 8;
  float4 a = *(const float4*)&src[base];
  float4 b = *(const float4*)&src[base + 4];
  float m = (a.x + a.y + a.z + a.w + b.x + b.y + b.z + b.w) * 0.125f;
  float q = (a.x * a.x + a.y * a.y + a.z * a.z + a.w * a.w +
             b.x * b.x + b.y * b.y + b.z * b.z + b.w * b.w) * 0.125f - m * m;
  float r = rsqrtf(q + 1e-5f);
  a.x = (a.x - m) * r; a.y = (a.y - m) * r; a.z = (a.z - m) * r; a.w = (a.w - m) * r;
  b.x = (b.x - m) * r; b.y = (b.y - m) * r; b.z = (b.z - m) * r; b.w = (b.w - m) * r;
  *(float4*)&dst[base] = a;
  *(float4*)&dst[base + 4] = b;
}

__global__ __launch_bounds__(256) void bcast_add_k(float* __restrict__ XT, const float* __restrict__ y3n,
                                                   const float* __restrict__ gate) {
  int i4 = blockIdx.x * 256 + threadIdx.x;
  int flat = i4 * 4;
  int r = flat >> 16, c = flat & 255;
  float g = gate[0];
  float4 v = ((float4*)XT)[i4];
  float4 a = *(const float4*)&y3n[r * 256 + c];
  v.x += g * a.x; v.y += g * a.y; v.z += g * a.z; v.w += g * a.w;
  ((float4*)XT)[i4] = v;
}

__global__ __launch_bounds__(256) void gn_stats_xt_k(const float* __restrict__ X, float* __restrict__ stats) {
  __shared__ float sbuf[8];
  int bx = blockIdx.x;
  int b = bx >> 11, g = (bx >> 6) & 31, f = bx & 63;
  size_t base = (size_t)(b * 64 + f) * 65536 + g * 8;
  float s = 0.f, ss = 0.f;
  for (int i = threadIdx.x; i < 2048; i += 256) {
    int t = i >> 3, c = i & 7;
    float v = X[base + t * 256 + c];
    s += v; ss += v * v;
  }
  blockReduce2(s, ss, sbuf);
  if (threadIdx.x == 0) { atomicAdd(&stats[b * 32 + g], s); atomicAdd(&stats[128 + b * 32 + g], ss); }
}

// ---------------- launch ----------------
extern "C" void kernel_launch(void* const* d_in, const int* in_sizes, int n_in,
                              void* d_out, int out_size, void* d_ws, size_t ws_size,
                              hipStream_t stream) {
  (void)in_sizes; (void)n_in; (void)out_size;
  const float* x        = (const float*)d_in[0];
  const float* temb     = (const float*)d_in[1];
  const float* conv1_w  = (const float*)d_in[2];
  const float* conv1_b  = (const float*)d_in[3];
  const float* conv2_w  = (const float*)d_in[4];
  const float* g_diff   = (const float*)d_in[5];
  const float* g_res    = (const float*)d_in[6];
  const float* g2       = (const float*)d_in[7];
  const float* g3       = (const float*)d_in[8];
  const float* qkv2_w   = (const float*)d_in[9];
  const float* qkv2_b   = (const float*)d_in[10];
  const float* out2_w   = (const float*)d_in[11];
  const float* qkv3_w   = (const float*)d_in[12];
  const float* qkv3_b   = (const float*)d_in[13];
  const float* out3_w   = (const float*)d_in[14];
  const float* lsa_qkv_w = (const float*)d_in[15];
  const float* lsa_out_w = (const float*)d_in[16];
  float* out = (float*)d_out;
  float* ws = (float*)d_ws;

  int NCHv = 4;
  {
    auto need = [](int nch) -> size_t {
      size_t rows = 65536 / nch;
      size_t uslots = rows * 512;
      if (uslots < 8388608) uslots = 8388608;
      return 4ull * ((size_t)NN + uslots + 950272 + 198000);
    };
    if (ws_size >= need(1)) NCHv = 1;
    else if (ws_size >= need(2)) NCHv = 2;
  }
  const size_t rows = 65536 / NCHv;

  float* W = ws;                                  // NN fp32 trunk
  float* U = ws + (size_t)NN;                     // union region
  unsigned short* XC  = (unsigned short*)U;       // NN bf16 (conv staging)
  unsigned short* QB  = (unsigned short*)U;       // rows*768 bf16 (qkv)
  unsigned short* O2B = (unsigned short*)(U + rows * 384);  // rows*256 bf16
  size_t uslots = rows * 512; if (uslots < 8388608) uslots = 8388608;
  float* WREG = U + uslots;
  unsigned short* WB1   = (unsigned short*)WREG;
  unsigned short* WB2   = WB1 + 589824;
  unsigned short* QKV2T = WB2 + 589824;
  unsigned short* OUT2T = QKV2T + 196608;
  unsigned short* QKV3T = OUT2T + 65536;
  unsigned short* LSAQT = QKV3T + 196608;
  unsigned short* LSAOT = LSAQT + 196608;
  float* Y3    = WREG + 950272;
  float* Y3O   = Y3 + 65536;
  float* Y3N   = Y3O + 65536;
  float* STATS = Y3N + 65536;                     // 1024 floats: ST0..ST3
  float* ST0 = STATS, *ST1 = STATS + 256, *ST2 = STATS + 512, *ST3 = STATS + 768;
  float* D = out;                                 // d_out as scratch until final stage

  dim3 b256(256);
  prep_all_k<<<7428, b256, 0, stream>>>(conv1_w, conv2_w, qkv2_w, out2_w, qkv3_w,
                                        lsa_qkv_w, lsa_out_w,
                                        WB1, WB2, QKV2T, OUT2T, QKV3T, LSAQT, LSAOT, STATS);

  // ---- residual block (conv output stats fused into conv epilogue) ----
  gn_stats_contig<<<1024, b256, 0, stream>>>(x, ST0);
  gn_apply_tr_k<<<16384, b256, 0, stream>>>(x, ST0, XC, 1e-6f);
  conv3x3_mfma_k<<<dim3(64, 8), b256, 0, stream>>>(XC, WB1, conv1_b, temb, g_diff, W, ST1, 1);
  gn_apply_tr_k<<<16384, b256, 0, stream>>>(W, ST1, XC, 1e-6f);
  conv3x3_mfma_k<<<dim3(64, 8), b256, 0, stream>>>(XC, WB2, nullptr, nullptr, nullptr, W, ST2, 0);
  gn_tr_resid_k<<<16384, b256, 0, stream>>>(W, x, ST2, g_res, D, 1e-6f);  // D = xf

  // ---- layer2: freq attention ----
  for (int c = 0; c < NCHv; ++c) {
    float* XFr = D + (size_t)c * rows * 256;
    gemm_af32_k<<<dim3(6, rows / 128), b256, 0, stream>>>(XFr, 256, QKV2T, qkv2_b, QB, 768, nullptr, 0, 0.f);
    attn2_mfma_k<<<rows / 64, b256, 0, stream>>>(QB);
    gemm_abf16_k<<<dim3(2, rows / 128), b256, 0, stream>>>(QB, 768, OUT2T, XFr, nullptr, 256, g2);
  }

  // ---- layer3: global time attention ----
  xf_to_xt_k<<<16384, b256, 0, stream>>>(D, W);   // W = xt
  for (int c = 0; c < NCHv; ++c) {
    const float* XTr = W + (size_t)c * rows * 256;
    gemm_af32_k<<<dim3(6, rows / 128), b256, 0, stream>>>(XTr, 256, QKV3T, qkv3_b, QB, 768, nullptr, 0, 0.f);
    attn3_k<<<(rows / 256) * 8, b256, 0, stream>>>(QB, Y3, c * (int)(rows / 256));
  }
  gemm_k<<<dim3(4, 4), b256, 0, stream>>>(Y3, 256, out3_w, 256, nullptr, Y3O, 256);
  gn_rows_k<<<32, b256, 0, stream>>>(Y3O, Y3N, 8192);
  bcast_add_k<<<16384, b256, 0, stream>>>(W, Y3N, g3);

  // ---- layer4: LSA ----
  gn_stats_xt_k<<<8192, b256, 0, stream>>>(W, ST3);
  for (int c = 0; c < NCHv; ++c) {
    const float* XTr = W + (size_t)c * rows * 256;
    gemm_af32_k<<<dim3(6, rows / 128), b256, 0, stream>>>(XTr, 256, LSAQT, nullptr, QB, 768,
                                                          ST3, (int)(c * rows), 1e-5f);
    lsa_attn_k<<<(rows / 256) * 16, b256, 0, stream>>>(QB);
    gemm_abf16_k<<<dim3(2, rows / 128), b256, 0, stream>>>(QB, 768, LSAOT, nullptr, O2B, 256, nullptr);
    final_out_k<<<(rows / 256) * 64, b256, 0, stream>>>(W, O2B, out, c * (int)(rows / 256));
  }
}